// Round 1
// baseline (2009.165 us; speedup 1.0000x reference)
//
#include <hip/hip_runtime.h>
#include <hip/hip_bf16.h>
#include <math.h>

#define B_    2
#define L_    2048
#define DM    1024
#define DI    2048
#define NTOK  (B_*L_)     /* 4096 */
#define NST   16
#define DTR   64
#define XD    96          /* DTR + 2*NST */
#define DCONV 4
#define EPS   1e-5f

// ---------------------------------------------------------------------------
// RMSNorm: one block per token row of 1024
__global__ __launch_bounds__(256) void rmsnorm_kernel(const float* __restrict__ x,
    const float* __restrict__ nw, float* __restrict__ xn)
{
    const int row = blockIdx.x;
    const int tid = threadIdx.x;
    const float* xr = x + (size_t)row * DM;
    float4 v = *(const float4*)(xr + tid * 4);
    float s = v.x*v.x + v.y*v.y + v.z*v.z + v.w*v.w;
    #pragma unroll
    for (int m = 1; m < 64; m <<= 1) s += __shfl_xor(s, m);
    __shared__ float wsum[4];
    if ((tid & 63) == 0) wsum[tid >> 6] = s;
    __syncthreads();
    float tot = wsum[0] + wsum[1] + wsum[2] + wsum[3];
    float rs = rsqrtf(tot * (1.0f / DM) + EPS);
    float4 w = *(const float4*)(nw + tid * 4);
    float4 o = make_float4(v.x*rs*w.x, v.y*rs*w.y, v.z*rs*w.z, v.w*rs*w.w);
    *(float4*)(xn + (size_t)row * DM + tid * 4) = o;
}

// ---------------------------------------------------------------------------
// fp32 SGEMM: C[M,N] = A[M,K] @ B[K,N], all row-major. 128x128 tile, BK=8,
// 256 threads, 8x8 per thread as 2x2 quadrants of 4x4 (keeps LDS reads at
// <=2-way bank aliasing, free on CDNA4).
__global__ __launch_bounds__(256) void gemm128_f32(
    const float* __restrict__ A, const float* __restrict__ Bw,
    float* __restrict__ C, int M, int N, int K)
{
    __shared__ float As[8][128];
    __shared__ float Bs[8][128];
    const int tid  = threadIdx.x;
    const int row0 = blockIdx.y * 128;
    const int col0 = blockIdx.x * 128;
    const int ar = tid >> 1, ac = (tid & 1) * 4;    // A tile 128x8
    const int br = tid >> 5, bc = (tid & 31) * 4;   // B tile 8x128
    const int ty = tid >> 4, tx = tid & 15;
    float acc[2][2][4][4];
    #pragma unroll
    for (int a = 0; a < 2; ++a)
        #pragma unroll
        for (int b = 0; b < 2; ++b)
            #pragma unroll
            for (int i = 0; i < 4; ++i)
                #pragma unroll
                for (int j = 0; j < 4; ++j) acc[a][b][i][j] = 0.0f;

    const float* Aptr = A + (size_t)(row0 + ar) * K + ac;
    const float* Bptr = Bw + (size_t)br * N + col0 + bc;

    for (int k0 = 0; k0 < K; k0 += 8) {
        float4 av = *(const float4*)(Aptr + k0);
        float4 bv = *(const float4*)(Bptr + (size_t)k0 * N);
        As[ac + 0][ar] = av.x; As[ac + 1][ar] = av.y;
        As[ac + 2][ar] = av.z; As[ac + 3][ar] = av.w;
        *(float4*)&Bs[br][bc] = bv;
        __syncthreads();
        #pragma unroll
        for (int k = 0; k < 8; ++k) {
            float4 a0 = *(const float4*)&As[k][ty * 4];
            float4 a1 = *(const float4*)&As[k][64 + ty * 4];
            float4 b0 = *(const float4*)&Bs[k][tx * 4];
            float4 b1 = *(const float4*)&Bs[k][64 + tx * 4];
            float ax[2][4] = {{a0.x,a0.y,a0.z,a0.w},{a1.x,a1.y,a1.z,a1.w}};
            float bx[2][4] = {{b0.x,b0.y,b0.z,b0.w},{b1.x,b1.y,b1.z,b1.w}};
            #pragma unroll
            for (int ii = 0; ii < 2; ++ii)
                #pragma unroll
                for (int i = 0; i < 4; ++i)
                    #pragma unroll
                    for (int jj = 0; jj < 2; ++jj)
                        #pragma unroll
                        for (int j = 0; j < 4; ++j)
                            acc[ii][jj][i][j] = fmaf(ax[ii][i], bx[jj][j], acc[ii][jj][i][j]);
        }
        __syncthreads();
    }
    #pragma unroll
    for (int ii = 0; ii < 2; ++ii)
        #pragma unroll
        for (int i = 0; i < 4; ++i)
            #pragma unroll
            for (int jj = 0; jj < 2; ++jj) {
                int r = row0 + ii * 64 + ty * 4 + i;
                int c = col0 + jj * 64 + tx * 4;
                float4 o = make_float4(acc[ii][jj][i][0], acc[ii][jj][i][1],
                                       acc[ii][jj][i][2], acc[ii][jj][i][3]);
                *(float4*)(C + (size_t)r * N + c) = o;
            }
}

// ---------------------------------------------------------------------------
// causal depthwise conv1d (taps=4) + SiLU.  u = xz[:, 0:2048] (row stride 4096)
__global__ __launch_bounds__(256) void conv_silu_kernel(const float* __restrict__ xz,
    const float* __restrict__ cw, const float* __restrict__ cb, float* __restrict__ uc)
{
    int idx = blockIdx.x * 256 + threadIdx.x;   // over NTOK*DI
    int d = idx & (DI - 1);
    int t = idx >> 11;          // token index (DI = 2048)
    int l = t & (L_ - 1);
    int b = t >> 11;            // L_ = 2048
    float acc = cb[d];
    #pragma unroll
    for (int k = 0; k < DCONV; ++k) {
        int lp = l + k - (DCONV - 1);
        if (lp >= 0)
            acc = fmaf(xz[((size_t)(b * L_ + lp) << 12) + d], cw[d * DCONV + k], acc);
    }
    uc[idx] = acc / (1.0f + expf(-acc));   // silu
}

// ---------------------------------------------------------------------------
// x_proj: xdbl[4096,96] = uc[4096,2048] @ W[2048,96].  Block: 16 tokens,
// K-chunks of 128 staged in LDS; 192 of 256 threads compute (2 token-groups x 96 cols).
__global__ __launch_bounds__(256) void xproj_kernel(const float* __restrict__ uc,
    const float* __restrict__ W, float* __restrict__ xdbl)
{
    __shared__ float ul[16 * 128];
    const int tid = threadIdx.x;
    const int tok0 = blockIdx.x * 16;
    const int g = tid / 96;      // 0,1 compute; 2 = load-only helpers
    const int j = tid % 96;
    float acc[8] = {0,0,0,0,0,0,0,0};
    for (int k0 = 0; k0 < DI; k0 += 128) {
        __syncthreads();
        int pos = tid * 4;
        int tr = pos >> 7, kk = pos & 127;
        *(float4*)&ul[pos] = *(const float4*)(uc + (size_t)(tok0 + tr) * DI + k0 + kk);
        pos += 1024; tr = pos >> 7; kk = pos & 127;
        *(float4*)&ul[pos] = *(const float4*)(uc + (size_t)(tok0 + tr) * DI + k0 + kk);
        __syncthreads();
        if (g < 2) {
            for (int k = 0; k < 128; ++k) {
                float w = W[(size_t)(k0 + k) * XD + j];
                #pragma unroll
                for (int t = 0; t < 8; ++t)
                    acc[t] = fmaf(ul[(g * 8 + t) * 128 + k], w, acc[t]);
            }
        }
    }
    if (g < 2) {
        #pragma unroll
        for (int t = 0; t < 8; ++t)
            xdbl[(size_t)(tok0 + g * 8 + t) * XD + j] = acc[t];
    }
}

// ---------------------------------------------------------------------------
// dt_proj + softplus: dt[4096,2048] = softplus(xdbl[:, :64] @ dtw[64,2048] + dtb)
// Block: 16 tokens x 256 d-cols; xdbl delta rows staged in LDS.
__global__ __launch_bounds__(256) void dtproj_kernel(const float* __restrict__ xdbl,
    const float* __restrict__ dtw, const float* __restrict__ dtb, float* __restrict__ dt)
{
    __shared__ float xl[16 * 64];
    const int tid = threadIdx.x;
    const int tokblk = blockIdx.x >> 3;
    const int dblk = blockIdx.x & 7;
    const int tok0 = tokblk * 16;
    const int d = dblk * 256 + tid;
    {
        int pos = tid * 4;
        int tr = pos >> 6, rr = pos & 63;
        *(float4*)&xl[pos] = *(const float4*)(xdbl + (size_t)(tok0 + tr) * XD + rr);
    }
    __syncthreads();
    float acc[16];
    float bias = dtb[d];
    #pragma unroll
    for (int t = 0; t < 16; ++t) acc[t] = bias;
    for (int r = 0; r < DTR; ++r) {
        float w = dtw[(size_t)r * DI + d];
        #pragma unroll
        for (int t = 0; t < 16; ++t)
            acc[t] = fmaf(xl[t * 64 + r], w, acc[t]);
    }
    #pragma unroll
    for (int t = 0; t < 16; ++t) {
        float v = acc[t];
        float sp = (v > 20.0f) ? v : log1pf(expf(v));
        dt[(size_t)(tok0 + t) * DI + d] = sp;
    }
}

// ---------------------------------------------------------------------------
// Selective scan.  Block: one batch x 16 d-channels; thread = (d_i, n).
// h = exp(dt*A)*h + dt*u*B[n];  y = sum_n h*C[n];  yg = (y + u*D) * silu(res)
__global__ __launch_bounds__(256) void scan_kernel(
    const float* __restrict__ dt, const float* __restrict__ uc,
    const float* __restrict__ xdbl, const float* __restrict__ xz,
    const float* __restrict__ A_log, const float* __restrict__ Dp,
    float* __restrict__ yg)
{
    const int tid = threadIdx.x;
    const int di = tid >> 4, n = tid & 15;
    const int b = blockIdx.x >> 7;          // 128 d-blocks per batch
    const int dblk = blockIdx.x & 127;
    const int d = dblk * 16 + di;
    const float Av = -expf(A_log[d * NST + n]);
    const float Dv = Dp[d];
    float h = 0.0f;
    const size_t t0 = (size_t)b * L_;

    // prefetch step 0
    float dtv = dt[t0 * DI + d];
    float uv  = uc[t0 * DI + d];
    float Bv  = xdbl[t0 * XD + DTR + n];
    float Cv  = xdbl[t0 * XD + DTR + NST + n];
    float rv  = xz[(t0 << 12) + DI + d];

    for (int l = 0; l < L_; ++l) {
        float dtv_n = 0, uv_n = 0, Bv_n = 0, Cv_n = 0, rv_n = 0;
        if (l + 1 < L_) {
            size_t tn = t0 + l + 1;
            dtv_n = dt[tn * DI + d];
            uv_n  = uc[tn * DI + d];
            Bv_n  = xdbl[tn * XD + DTR + n];
            Cv_n  = xdbl[tn * XD + DTR + NST + n];
            rv_n  = xz[(tn << 12) + DI + d];
        }
        float dA = expf(dtv * Av);
        h = fmaf(dA, h, dtv * uv * Bv);
        float p = h * Cv;
        p += __shfl_xor(p, 1);
        p += __shfl_xor(p, 2);
        p += __shfl_xor(p, 4);
        p += __shfl_xor(p, 8);
        if (n == 0) {
            float y = fmaf(uv, Dv, p);
            float sig = 1.0f / (1.0f + expf(-rv));
            yg[(t0 + l) * DI + d] = y * rv * sig;
        }
        dtv = dtv_n; uv = uv_n; Bv = Bv_n; Cv = Cv_n; rv = rv_n;
    }
}

// ---------------------------------------------------------------------------
extern "C" void kernel_launch(void* const* d_in, const int* in_sizes, int n_in,
                              void* d_out, int out_size, void* d_ws, size_t ws_size,
                              hipStream_t stream)
{
    const float* x    = (const float*)d_in[0];
    const float* nw   = (const float*)d_in[1];
    const float* ipw  = (const float*)d_in[2];
    const float* cw   = (const float*)d_in[3];
    const float* cb   = (const float*)d_in[4];
    const float* xpw  = (const float*)d_in[5];
    const float* dtw  = (const float*)d_in[6];
    const float* dtb  = (const float*)d_in[7];
    const float* alog = (const float*)d_in[8];
    const float* dpar = (const float*)d_in[9];
    const float* opw  = (const float*)d_in[10];
    float* out = (float*)d_out;

    float* ws    = (float*)d_ws;
    float* xn    = ws;                        // 4096x1024
    float* xz    = xn    + (size_t)NTOK * DM;     // 4096x4096 (u | res)
    float* uc    = xz    + (size_t)NTOK * 2 * DI; // 4096x2048
    float* xdbl  = uc    + (size_t)NTOK * DI;     // 4096x96
    float* dtbuf = xdbl  + (size_t)NTOK * XD;     // 4096x2048
    float* yg    = dtbuf + (size_t)NTOK * DI;     // 4096x2048
    // total ~186.1 MB of d_ws

    rmsnorm_kernel<<<NTOK, 256, 0, stream>>>(x, nw, xn);

    dim3 g1(2 * DI / 128, NTOK / 128);   // (32, 32)
    gemm128_f32<<<g1, 256, 0, stream>>>(xn, ipw, xz, NTOK, 2 * DI, DM);

    conv_silu_kernel<<<NTOK * DI / 256, 256, 0, stream>>>(xz, cw, cb, uc);

    xproj_kernel<<<NTOK / 16, 256, 0, stream>>>(uc, xpw, xdbl);

    dtproj_kernel<<<(NTOK / 16) * (DI / 256), 256, 0, stream>>>(xdbl, dtw, dtb, dtbuf);

    scan_kernel<<<B_ * (DI / 16), 256, 0, stream>>>(dtbuf, uc, xdbl, xz, alog, dpar, yg);

    dim3 g2(DM / 128, NTOK / 128);       // (8, 32)
    gemm128_f32<<<g2, 256, 0, stream>>>(yg, opw, out, NTOK, DM, DI);
}

// Round 2
// 748.862 us; speedup vs baseline: 2.6830x; 2.6830x over previous
//
#include <hip/hip_runtime.h>
#include <hip/hip_bf16.h>
#include <math.h>

#define B_    2
#define L_    2048
#define DM    1024
#define DI    2048
#define NTOK  (B_*L_)     /* 4096 */
#define NST   16
#define DTR   64
#define XD    96          /* DTR + 2*NST */
#define DCONV 4
#define EPS   1e-5f
#define CH    64          /* scan chunk length */
#define NCH   (L_/CH)     /* 32 */

typedef __attribute__((ext_vector_type(8))) short bf16x8;
typedef __attribute__((ext_vector_type(4))) float f32x4;
typedef unsigned short ushort_t;

__device__ __forceinline__ unsigned short f2bf(float f) {
    union { float f; unsigned int u; } v; v.f = f;
    unsigned int r = v.u + 0x7fffu + ((v.u >> 16) & 1u);
    return (unsigned short)(r >> 16);
}

// ---------------------------------------------------------------------------
// RMSNorm -> bf16 output (feeds MFMA GEMM1 A-operand)
__global__ __launch_bounds__(256) void rmsnorm_bf16(const float* __restrict__ x,
    const float* __restrict__ nw, unsigned short* __restrict__ xn)
{
    const int row = blockIdx.x;
    const int tid = threadIdx.x;
    const float* xr = x + (size_t)row * DM;
    float4 v = *(const float4*)(xr + tid * 4);
    float s = v.x*v.x + v.y*v.y + v.z*v.z + v.w*v.w;
    #pragma unroll
    for (int m = 1; m < 64; m <<= 1) s += __shfl_xor(s, m);
    __shared__ float wsum[4];
    if ((tid & 63) == 0) wsum[tid >> 6] = s;
    __syncthreads();
    float tot = wsum[0] + wsum[1] + wsum[2] + wsum[3];
    float rs = rsqrtf(tot * (1.0f / DM) + EPS);
    float4 w = *(const float4*)(nw + tid * 4);
    ushort4 o;
    o.x = f2bf(v.x*rs*w.x); o.y = f2bf(v.y*rs*w.y);
    o.z = f2bf(v.z*rs*w.z); o.w = f2bf(v.w*rs*w.w);
    *(ushort4*)(xn + (size_t)row * DM + tid * 4) = o;
}

// ---------------------------------------------------------------------------
// Transpose + cast: W[K][N] fp32 -> Wt[N][K] bf16   (32x32 LDS tiles)
__global__ __launch_bounds__(256) void transpose_cast(const float* __restrict__ W,
    unsigned short* __restrict__ Wt, int K, int N)
{
    __shared__ float tile[32][33];
    const int tid = threadIdx.x;
    const int k0 = blockIdx.y * 32;
    const int n0 = blockIdx.x * 32;
    #pragma unroll
    for (int p = 0; p < 4; ++p) {
        int idx = p * 256 + tid;
        int r = idx >> 5, c = idx & 31;
        tile[c][r] = W[(size_t)(k0 + r) * N + n0 + c];
    }
    __syncthreads();
    #pragma unroll
    for (int p = 0; p < 4; ++p) {
        int idx = p * 256 + tid;
        int r = idx >> 5, c = idx & 31;   // r = n-row, c = k-col
        Wt[(size_t)(n0 + r) * K + k0 + c] = f2bf(tile[r][c]);
    }
}

// ---------------------------------------------------------------------------
// bf16 MFMA GEMM (m97 structure): C_f32[M,N] = A_bf16[M,K] @ Bt_bf16[N,K]^T
// 128x128 tile, BK=32, 256 threads = 4 waves (2x2), 16x16x32 MFMA, 4x4 frags.
// Staging via global_load_lds width 16 (linear LDS dest = wave base + lane*16).
__global__ __launch_bounds__(256) void gemm_bf16t(
    const unsigned short* __restrict__ A, const unsigned short* __restrict__ Bt,
    float* __restrict__ C, int M, int N, int K)
{
    __shared__ unsigned short Al[128 * 32];
    __shared__ unsigned short Bl[128 * 32];
    const int tid  = threadIdx.x;
    const int lane = tid & 63;
    const int wid  = tid >> 6;
    const int wr = wid >> 1, wc = wid & 1;
    const int row0 = blockIdx.y * 128;
    const int col0 = blockIdx.x * 128;

    f32x4 acc[4][4];
    #pragma unroll
    for (int m = 0; m < 4; ++m)
        #pragma unroll
        for (int n = 0; n < 4; ++n)
            acc[m][n] = (f32x4){0.f, 0.f, 0.f, 0.f};

    // staging: wave w covers rows [w*32, w*32+32): two 1KB issues of 16 rows.
    // within a 1KB issue: lane l -> row l/4, k-chunk (l&3)*8  (== lane*16 bytes)
    const int srow = wid * 32 + (lane >> 2);
    const int kc   = (lane & 3) * 8;
    const unsigned short* Ab = A  + (size_t)(row0 + srow) * K + kc;
    const unsigned short* Bb = Bt + (size_t)(col0 + srow) * K + kc;
    unsigned short* AlB = &Al[wid * 32 * 32];   // wave-uniform LDS base
    unsigned short* BlB = &Bl[wid * 32 * 32];

    for (int kt = 0; kt < K; kt += 32) {
        __builtin_amdgcn_global_load_lds(
            (const __attribute__((address_space(1))) void*)(Ab + kt),
            (__attribute__((address_space(3))) void*)(AlB), 16, 0, 0);
        __builtin_amdgcn_global_load_lds(
            (const __attribute__((address_space(1))) void*)(Ab + kt + (size_t)16 * K),
            (__attribute__((address_space(3))) void*)(AlB + 16 * 32), 16, 0, 0);
        __builtin_amdgcn_global_load_lds(
            (const __attribute__((address_space(1))) void*)(Bb + kt),
            (__attribute__((address_space(3))) void*)(BlB), 16, 0, 0);
        __builtin_amdgcn_global_load_lds(
            (const __attribute__((address_space(1))) void*)(Bb + kt + (size_t)16 * K),
            (__attribute__((address_space(3))) void*)(BlB + 16 * 32), 16, 0, 0);
        __syncthreads();

        const int fr = lane & 15, kg = (lane >> 4) * 8;
        bf16x8 a[4], b[4];
        #pragma unroll
        for (int m = 0; m < 4; ++m)
            a[m] = *(const bf16x8*)&Al[(wr * 64 + m * 16 + fr) * 32 + kg];
        #pragma unroll
        for (int n = 0; n < 4; ++n)
            b[n] = *(const bf16x8*)&Bl[(wc * 64 + n * 16 + fr) * 32 + kg];
        #pragma unroll
        for (int m = 0; m < 4; ++m)
            #pragma unroll
            for (int n = 0; n < 4; ++n)
                acc[m][n] = __builtin_amdgcn_mfma_f32_16x16x32_bf16(a[m], b[n], acc[m][n], 0, 0, 0);
        __syncthreads();
    }

    const int fr = lane & 15, rq = lane >> 4;
    #pragma unroll
    for (int m = 0; m < 4; ++m) {
        int r0 = row0 + wr * 64 + m * 16 + rq * 4;
        #pragma unroll
        for (int n = 0; n < 4; ++n) {
            int cc = col0 + wc * 64 + n * 16 + fr;
            #pragma unroll
            for (int r = 0; r < 4; ++r)
                C[(size_t)(r0 + r) * N + cc] = acc[m][n][r];
        }
    }
}

// ---------------------------------------------------------------------------
// causal depthwise conv1d (taps=4) + SiLU.  u = xz[:, 0:2048] (row stride 4096)
__global__ __launch_bounds__(256) void conv_silu_kernel(const float* __restrict__ xz,
    const float* __restrict__ cw, const float* __restrict__ cb, float* __restrict__ uc)
{
    int idx = blockIdx.x * 256 + threadIdx.x;   // over NTOK*DI
    int d = idx & (DI - 1);
    int t = idx >> 11;
    int l = t & (L_ - 1);
    int b = t >> 11;
    float acc = cb[d];
    #pragma unroll
    for (int k = 0; k < DCONV; ++k) {
        int lp = l + k - (DCONV - 1);
        if (lp >= 0)
            acc = fmaf(xz[((size_t)(b * L_ + lp) << 12) + d], cw[d * DCONV + k], acc);
    }
    uc[idx] = acc / (1.0f + expf(-acc));
}

// ---------------------------------------------------------------------------
// x_proj: xdbl[4096,96] = uc[4096,2048] @ W[2048,96]
__global__ __launch_bounds__(256) void xproj_kernel(const float* __restrict__ uc,
    const float* __restrict__ W, float* __restrict__ xdbl)
{
    __shared__ float ul[16 * 128];
    const int tid = threadIdx.x;
    const int tok0 = blockIdx.x * 16;
    const int g = tid / 96;
    const int j = tid % 96;
    float acc[8] = {0,0,0,0,0,0,0,0};
    for (int k0 = 0; k0 < DI; k0 += 128) {
        __syncthreads();
        int pos = tid * 4;
        int tr = pos >> 7, kk = pos & 127;
        *(float4*)&ul[pos] = *(const float4*)(uc + (size_t)(tok0 + tr) * DI + k0 + kk);
        pos += 1024; tr = pos >> 7; kk = pos & 127;
        *(float4*)&ul[pos] = *(const float4*)(uc + (size_t)(tok0 + tr) * DI + k0 + kk);
        __syncthreads();
        if (g < 2) {
            for (int k = 0; k < 128; ++k) {
                float w = W[(size_t)(k0 + k) * XD + j];
                #pragma unroll
                for (int t = 0; t < 8; ++t)
                    acc[t] = fmaf(ul[(g * 8 + t) * 128 + k], w, acc[t]);
            }
        }
    }
    if (g < 2) {
        #pragma unroll
        for (int t = 0; t < 8; ++t)
            xdbl[(size_t)(tok0 + g * 8 + t) * XD + j] = acc[t];
    }
}

// ---------------------------------------------------------------------------
// dt_proj + softplus
__global__ __launch_bounds__(256) void dtproj_kernel(const float* __restrict__ xdbl,
    const float* __restrict__ dtw, const float* __restrict__ dtb, float* __restrict__ dt)
{
    __shared__ float xl[16 * 64];
    const int tid = threadIdx.x;
    const int tokblk = blockIdx.x >> 3;
    const int dblk = blockIdx.x & 7;
    const int tok0 = tokblk * 16;
    const int d = dblk * 256 + tid;
    {
        int pos = tid * 4;
        int tr = pos >> 6, rr = pos & 63;
        *(float4*)&xl[pos] = *(const float4*)(xdbl + (size_t)(tok0 + tr) * XD + rr);
    }
    __syncthreads();
    float acc[16];
    float bias = dtb[d];
    #pragma unroll
    for (int t = 0; t < 16; ++t) acc[t] = bias;
    for (int r = 0; r < DTR; ++r) {
        float w = dtw[(size_t)r * DI + d];
        #pragma unroll
        for (int t = 0; t < 16; ++t)
            acc[t] = fmaf(xl[t * 64 + r], w, acc[t]);
    }
    #pragma unroll
    for (int t = 0; t < 16; ++t) {
        float v = acc[t];
        float sp = (v > 20.0f) ? v : log1pf(expf(v));
        dt[(size_t)(tok0 + t) * DI + d] = sp;
    }
}

// ---------------------------------------------------------------------------
// Chunked selective scan.  Thread = one d-channel, 16 states in registers.
// Pass A: per-chunk local scan from h=0; emit end-state hA and decay product PA.
__global__ __launch_bounds__(256) void scan_passA(
    const float* __restrict__ dt, const float* __restrict__ uc,
    const float* __restrict__ xdbl, const float* __restrict__ A_log,
    float* __restrict__ hA, float* __restrict__ PA)
{
    const int tid = threadIdx.x;
    const int bid = blockIdx.x;            // 512 = B * NCH * 8
    const int dblk = bid & 7;
    const int c = (bid >> 3) & (NCH - 1);
    const int b = bid >> 8;
    const int d = dblk * 256 + tid;
    const size_t t0 = (size_t)b * L_ + (size_t)c * CH;

    float Av[NST];
    {
        const float4* ap = (const float4*)(A_log + (size_t)d * NST);
        float4 a0 = ap[0], a1 = ap[1], a2 = ap[2], a3 = ap[3];
        Av[0]=-expf(a0.x); Av[1]=-expf(a0.y); Av[2]=-expf(a0.z); Av[3]=-expf(a0.w);
        Av[4]=-expf(a1.x); Av[5]=-expf(a1.y); Av[6]=-expf(a1.z); Av[7]=-expf(a1.w);
        Av[8]=-expf(a2.x); Av[9]=-expf(a2.y); Av[10]=-expf(a2.z); Av[11]=-expf(a2.w);
        Av[12]=-expf(a3.x); Av[13]=-expf(a3.y); Av[14]=-expf(a3.z); Av[15]=-expf(a3.w);
    }
    float h[NST], P[NST];
    #pragma unroll
    for (int n = 0; n < NST; ++n) { h[n] = 0.f; P[n] = 1.f; }

    float dtv[4], uv[4];
    float4 Bq[2][4];
    #pragma unroll
    for (int j = 0; j < 4; ++j) {
        size_t t = t0 + j;
        dtv[j] = dt[t * DI + d];
        uv[j]  = uc[t * DI + d];
    }
    #pragma unroll
    for (int j = 0; j < 2; ++j) {
        const float4* xr = (const float4*)(xdbl + (t0 + j) * XD + DTR);
        Bq[j][0] = xr[0]; Bq[j][1] = xr[1]; Bq[j][2] = xr[2]; Bq[j][3] = xr[3];
    }

    #pragma unroll 4
    for (int l = 0; l < CH; ++l) {
        const int s2 = l & 1, s4 = l & 3;
        float dtc = dtv[s4], uvc = uv[s4];
        float bc[16];
        bc[0]=Bq[s2][0].x; bc[1]=Bq[s2][0].y; bc[2]=Bq[s2][0].z; bc[3]=Bq[s2][0].w;
        bc[4]=Bq[s2][1].x; bc[5]=Bq[s2][1].y; bc[6]=Bq[s2][1].z; bc[7]=Bq[s2][1].w;
        bc[8]=Bq[s2][2].x; bc[9]=Bq[s2][2].y; bc[10]=Bq[s2][2].z; bc[11]=Bq[s2][2].w;
        bc[12]=Bq[s2][3].x; bc[13]=Bq[s2][3].y; bc[14]=Bq[s2][3].z; bc[15]=Bq[s2][3].w;
        if (l + 4 < CH) {
            size_t t = t0 + l + 4;
            dtv[s4] = dt[t * DI + d];
            uv[s4]  = uc[t * DI + d];
        }
        if (l + 2 < CH) {
            const float4* xr = (const float4*)(xdbl + (t0 + l + 2) * XD + DTR);
            Bq[s2][0] = xr[0]; Bq[s2][1] = xr[1]; Bq[s2][2] = xr[2]; Bq[s2][3] = xr[3];
        }
        float dtu = dtc * uvc;
        #pragma unroll
        for (int n = 0; n < NST; ++n) {
            float dA = expf(dtc * Av[n]);
            h[n] = fmaf(dA, h[n], dtu * bc[n]);
            P[n] *= dA;
        }
    }
    size_t obase = ((size_t)(b * NCH + c) * DI + d) * NST;
    float4* hp = (float4*)&hA[obase];
    hp[0] = make_float4(h[0], h[1], h[2], h[3]);
    hp[1] = make_float4(h[4], h[5], h[6], h[7]);
    hp[2] = make_float4(h[8], h[9], h[10], h[11]);
    hp[3] = make_float4(h[12], h[13], h[14], h[15]);
    float4* pp = (float4*)&PA[obase];
    pp[0] = make_float4(P[0], P[1], P[2], P[3]);
    pp[1] = make_float4(P[4], P[5], P[6], P[7]);
    pp[2] = make_float4(P[8], P[9], P[10], P[11]);
    pp[3] = make_float4(P[12], P[13], P[14], P[15]);
}

// Pass B: combine chunk boundaries.  Thread = (b,d,n); serial over 32 chunks.
__global__ __launch_bounds__(256) void scan_passB(
    const float* __restrict__ hA, const float* __restrict__ PA,
    float* __restrict__ hin)
{
    int g = blockIdx.x * 256 + threadIdx.x;    // B*DI*NST = 65536
    int b = g >> 15;
    int rest = g & 32767;                      // d*16 + n
    float h = 0.f;
    for (int c = 0; c < NCH; ++c) {
        size_t idx = ((size_t)(b * NCH + c) * DI) * NST + rest;
        hin[idx] = h;
        h = fmaf(PA[idx], h, hA[idx]);
    }
}

// Pass C: rescan chunks from hin; emit gated bf16 output for out_proj GEMM.
__global__ __launch_bounds__(256) void scan_passC(
    const float* __restrict__ dt, const float* __restrict__ uc,
    const float* __restrict__ xdbl, const float* __restrict__ xz,
    const float* __restrict__ A_log, const float* __restrict__ Dp,
    const float* __restrict__ hin, unsigned short* __restrict__ yg)
{
    const int tid = threadIdx.x;
    const int bid = blockIdx.x;
    const int dblk = bid & 7;
    const int c = (bid >> 3) & (NCH - 1);
    const int b = bid >> 8;
    const int d = dblk * 256 + tid;
    const size_t t0 = (size_t)b * L_ + (size_t)c * CH;

    float Av[NST];
    {
        const float4* ap = (const float4*)(A_log + (size_t)d * NST);
        float4 a0 = ap[0], a1 = ap[1], a2 = ap[2], a3 = ap[3];
        Av[0]=-expf(a0.x); Av[1]=-expf(a0.y); Av[2]=-expf(a0.z); Av[3]=-expf(a0.w);
        Av[4]=-expf(a1.x); Av[5]=-expf(a1.y); Av[6]=-expf(a1.z); Av[7]=-expf(a1.w);
        Av[8]=-expf(a2.x); Av[9]=-expf(a2.y); Av[10]=-expf(a2.z); Av[11]=-expf(a2.w);
        Av[12]=-expf(a3.x); Av[13]=-expf(a3.y); Av[14]=-expf(a3.z); Av[15]=-expf(a3.w);
    }
    const float Dv = Dp[d];
    float h[NST];
    {
        size_t ibase = ((size_t)(b * NCH + c) * DI + d) * NST;
        const float4* hp = (const float4*)&hin[ibase];
        float4 h0 = hp[0], h1 = hp[1], h2 = hp[2], h3 = hp[3];
        h[0]=h0.x; h[1]=h0.y; h[2]=h0.z; h[3]=h0.w;
        h[4]=h1.x; h[5]=h1.y; h[6]=h1.z; h[7]=h1.w;
        h[8]=h2.x; h[9]=h2.y; h[10]=h2.z; h[11]=h2.w;
        h[12]=h3.x; h[13]=h3.y; h[14]=h3.z; h[15]=h3.w;
    }

    float dtv[4], uv[4], rv[4];
    float4 Bq[2][4], Cq[2][4];
    #pragma unroll
    for (int j = 0; j < 4; ++j) {
        size_t t = t0 + j;
        dtv[j] = dt[t * DI + d];
        uv[j]  = uc[t * DI + d];
        rv[j]  = xz[(t << 12) + DI + d];
    }
    #pragma unroll
    for (int j = 0; j < 2; ++j) {
        const float4* xr = (const float4*)(xdbl + (t0 + j) * XD + DTR);
        Bq[j][0] = xr[0]; Bq[j][1] = xr[1]; Bq[j][2] = xr[2]; Bq[j][3] = xr[3];
        Cq[j][0] = xr[4]; Cq[j][1] = xr[5]; Cq[j][2] = xr[6]; Cq[j][3] = xr[7];
    }

    #pragma unroll 4
    for (int l = 0; l < CH; ++l) {
        const int s2 = l & 1, s4 = l & 3;
        float dtc = dtv[s4], uvc = uv[s4], rvc = rv[s4];
        float bc[16], cc[16];
        bc[0]=Bq[s2][0].x; bc[1]=Bq[s2][0].y; bc[2]=Bq[s2][0].z; bc[3]=Bq[s2][0].w;
        bc[4]=Bq[s2][1].x; bc[5]=Bq[s2][1].y; bc[6]=Bq[s2][1].z; bc[7]=Bq[s2][1].w;
        bc[8]=Bq[s2][2].x; bc[9]=Bq[s2][2].y; bc[10]=Bq[s2][2].z; bc[11]=Bq[s2][2].w;
        bc[12]=Bq[s2][3].x; bc[13]=Bq[s2][3].y; bc[14]=Bq[s2][3].z; bc[15]=Bq[s2][3].w;
        cc[0]=Cq[s2][0].x; cc[1]=Cq[s2][0].y; cc[2]=Cq[s2][0].z; cc[3]=Cq[s2][0].w;
        cc[4]=Cq[s2][1].x; cc[5]=Cq[s2][1].y; cc[6]=Cq[s2][1].z; cc[7]=Cq[s2][1].w;
        cc[8]=Cq[s2][2].x; cc[9]=Cq[s2][2].y; cc[10]=Cq[s2][2].z; cc[11]=Cq[s2][2].w;
        cc[12]=Cq[s2][3].x; cc[13]=Cq[s2][3].y; cc[14]=Cq[s2][3].z; cc[15]=Cq[s2][3].w;
        if (l + 4 < CH) {
            size_t t = t0 + l + 4;
            dtv[s4] = dt[t * DI + d];
            uv[s4]  = uc[t * DI + d];
            rv[s4]  = xz[(t << 12) + DI + d];
        }
        if (l + 2 < CH) {
            const float4* xr = (const float4*)(xdbl + (t0 + l + 2) * XD + DTR);
            Bq[s2][0] = xr[0]; Bq[s2][1] = xr[1]; Bq[s2][2] = xr[2]; Bq[s2][3] = xr[3];
            Cq[s2][0] = xr[4]; Cq[s2][1] = xr[5]; Cq[s2][2] = xr[6]; Cq[s2][3] = xr[7];
        }
        float dtu = dtc * uvc;
        float y = 0.f;
        #pragma unroll
        for (int n = 0; n < NST; ++n) {
            float dA = expf(dtc * Av[n]);
            h[n] = fmaf(dA, h[n], dtu * bc[n]);
            y = fmaf(h[n], cc[n], y);
        }
        y = fmaf(uvc, Dv, y);
        float sig = 1.0f / (1.0f + expf(-rvc));
        yg[(t0 + l) * DI + d] = f2bf(y * rvc * sig);
    }
}

// ---------------------------------------------------------------------------
extern "C" void kernel_launch(void* const* d_in, const int* in_sizes, int n_in,
                              void* d_out, int out_size, void* d_ws, size_t ws_size,
                              hipStream_t stream)
{
    const float* x    = (const float*)d_in[0];
    const float* nw   = (const float*)d_in[1];
    const float* ipw  = (const float*)d_in[2];
    const float* cw   = (const float*)d_in[3];
    const float* cb   = (const float*)d_in[4];
    const float* xpw  = (const float*)d_in[5];
    const float* dtw  = (const float*)d_in[6];
    const float* dtb  = (const float*)d_in[7];
    const float* alog = (const float*)d_in[8];
    const float* dpar = (const float*)d_in[9];
    const float* opw  = (const float*)d_in[10];
    float* out = (float*)d_out;

    char* p = (char*)d_ws;
    float* xz    = (float*)p;  p += (size_t)NTOK * 2 * DI * 4;     // 67.1 MB
    float* uc    = (float*)p;  p += (size_t)NTOK * DI * 4;         // 33.6 MB
    float* xdbl  = (float*)p;  p += (size_t)NTOK * XD * 4;         //  1.6 MB
    float* dtbuf = (float*)p;  p += (size_t)NTOK * DI * 4;         // 33.6 MB
    float* hin   = (float*)p;  p += (size_t)B_ * NCH * DI * NST * 4; // 8.4 MB
    unsigned short* yg   = (unsigned short*)p;  p += (size_t)NTOK * DI * 2;   // 16.8 MB
    unsigned short* xnb  = (unsigned short*)p;  p += (size_t)NTOK * DM * 2;   //  8.4 MB
    unsigned short* ipwt = (unsigned short*)p;  p += (size_t)DM * 2 * DI * 2; //  8.4 MB
    unsigned short* opwt = (unsigned short*)p;  p += (size_t)DI * DM * 2;     //  4.2 MB
    // aliases: dead after GEMM1, reused by scan pass A/B
    float* hA = (float*)xnb;    // 8.4 MB needed, 8.4 MB available
    float* PA = (float*)ipwt;   // 8.4 MB needed, 8.4 MB available

    // weight transpose-casts
    transpose_cast<<<dim3(2 * DI / 32, DM / 32), 256, 0, stream>>>(ipw, ipwt, DM, 2 * DI);
    transpose_cast<<<dim3(DM / 32, DI / 32), 256, 0, stream>>>(opw, opwt, DI, DM);

    rmsnorm_bf16<<<NTOK, 256, 0, stream>>>(x, nw, xnb);

    // in_proj: [4096,1024] @ [1024,4096] -> xz
    gemm_bf16t<<<dim3(2 * DI / 128, NTOK / 128), 256, 0, stream>>>(xnb, ipwt, xz, NTOK, 2 * DI, DM);

    conv_silu_kernel<<<NTOK * DI / 256, 256, 0, stream>>>(xz, cw, cb, uc);
    xproj_kernel<<<NTOK / 16, 256, 0, stream>>>(uc, xpw, xdbl);
    dtproj_kernel<<<(NTOK / 16) * (DI / 256), 256, 0, stream>>>(xdbl, dtw, dtb, dtbuf);

    scan_passA<<<B_ * NCH * (DI / 256), 256, 0, stream>>>(dtbuf, uc, xdbl, alog, hA, PA);
    scan_passB<<<B_ * DI * NST / 256, 256, 0, stream>>>(hA, PA, hin);
    scan_passC<<<B_ * NCH * (DI / 256), 256, 0, stream>>>(dtbuf, uc, xdbl, xz, alog, dpar, hin, yg);

    // out_proj: [4096,2048] @ [2048,1024] -> out
    gemm_bf16t<<<dim3(DM / 128, NTOK / 128), 256, 0, stream>>>(yg, opwt, out, NTOK, DM, DI);
}

// Round 7
// 562.146 us; speedup vs baseline: 3.5741x; 1.3321x over previous
//
#include <hip/hip_runtime.h>
#include <hip/hip_bf16.h>
#include <math.h>

#define B_    2
#define L_    2048
#define DM    1024
#define DI    2048
#define NTOK  (B_*L_)     /* 4096 */
#define NST   16
#define DTR   64
#define XD    96          /* DTR + 2*NST */
#define DCONV 4
#define EPS   1e-5f
#define CH    64          /* scan chunk length */
#define NCH   (L_/CH)     /* 32 */
#define KSP   8           /* xproj K-split */

typedef __attribute__((ext_vector_type(8))) short bf16x8;
typedef __attribute__((ext_vector_type(4))) float f32x4;

__device__ __forceinline__ unsigned short f2bf(float f) {
    union { float f; unsigned int u; } v; v.f = f;
    unsigned int r = v.u + 0x7fffu + ((v.u >> 16) & 1u);
    return (unsigned short)(r >> 16);
}
__device__ __forceinline__ float bf2f(unsigned short h) {
    union { unsigned int u; float f; } v; v.u = ((unsigned int)h) << 16;
    return v.f;
}

// ---------------------------------------------------------------------------
// RMSNorm -> bf16
__global__ __launch_bounds__(256) void rmsnorm_bf16(const float* __restrict__ x,
    const float* __restrict__ nw, unsigned short* __restrict__ xn)
{
    const int row = blockIdx.x;
    const int tid = threadIdx.x;
    const float* xr = x + (size_t)row * DM;
    float4 v = *(const float4*)(xr + tid * 4);
    float s = v.x*v.x + v.y*v.y + v.z*v.z + v.w*v.w;
    #pragma unroll
    for (int m = 1; m < 64; m <<= 1) s += __shfl_xor(s, m);
    __shared__ float wsum[4];
    if ((tid & 63) == 0) wsum[tid >> 6] = s;
    __syncthreads();
    float tot = wsum[0] + wsum[1] + wsum[2] + wsum[3];
    float rs = rsqrtf(tot * (1.0f / DM) + EPS);
    float4 w = *(const float4*)(nw + tid * 4);
    ushort4 o;
    o.x = f2bf(v.x*rs*w.x); o.y = f2bf(v.y*rs*w.y);
    o.z = f2bf(v.z*rs*w.z); o.w = f2bf(v.w*rs*w.w);
    *(ushort4*)(xn + (size_t)row * DM + tid * 4) = o;
}

// ---------------------------------------------------------------------------
// Transpose + cast: W[K][N] fp32 -> Wt[N][K] bf16
__global__ __launch_bounds__(256) void transpose_cast(const float* __restrict__ W,
    unsigned short* __restrict__ Wt, int K, int N)
{
    __shared__ float tile[32][33];
    const int tid = threadIdx.x;
    const int k0 = blockIdx.y * 32;
    const int n0 = blockIdx.x * 32;
    #pragma unroll
    for (int p = 0; p < 4; ++p) {
        int idx = p * 256 + tid;
        int r = idx >> 5, c = idx & 31;
        tile[c][r] = W[(size_t)(k0 + r) * N + n0 + c];
    }
    __syncthreads();
    #pragma unroll
    for (int p = 0; p < 4; ++p) {
        int idx = p * 256 + tid;
        int r = idx >> 5, c = idx & 31;
        Wt[(size_t)(n0 + r) * K + k0 + c] = f2bf(tile[r][c]);
    }
}

// Transpose + hi/lo split-cast: W[K][96] fp32 -> Wh/Wl[96][K] bf16
__global__ __launch_bounds__(256) void transpose_cast_hl(const float* __restrict__ W,
    unsigned short* __restrict__ Wh, unsigned short* __restrict__ Wl, int K, int N)
{
    __shared__ float tile[32][33];
    const int tid = threadIdx.x;
    const int k0 = blockIdx.y * 32;
    const int n0 = blockIdx.x * 32;
    #pragma unroll
    for (int p = 0; p < 4; ++p) {
        int idx = p * 256 + tid;
        int r = idx >> 5, c = idx & 31;
        tile[c][r] = W[(size_t)(k0 + r) * N + n0 + c];
    }
    __syncthreads();
    #pragma unroll
    for (int p = 0; p < 4; ++p) {
        int idx = p * 256 + tid;
        int r = idx >> 5, c = idx & 31;
        float v = tile[r][c];
        unsigned short h = f2bf(v);
        float lo = v - bf2f(h);
        size_t o = (size_t)(n0 + r) * K + k0 + c;
        Wh[o] = h;
        Wl[o] = f2bf(lo);
    }
}

// ---------------------------------------------------------------------------
// bf16 MFMA GEMM (m97 structure), 128x128 tile, BK=32
__global__ __launch_bounds__(256) void gemm_bf16t(
    const unsigned short* __restrict__ A, const unsigned short* __restrict__ Bt,
    float* __restrict__ C, int M, int N, int K)
{
    __shared__ unsigned short Al[128 * 32];
    __shared__ unsigned short Bl[128 * 32];
    const int tid  = threadIdx.x;
    const int lane = tid & 63;
    const int wid  = tid >> 6;
    const int wr = wid >> 1, wc = wid & 1;
    const int row0 = blockIdx.y * 128;
    const int col0 = blockIdx.x * 128;

    f32x4 acc[4][4];
    #pragma unroll
    for (int m = 0; m < 4; ++m)
        #pragma unroll
        for (int n = 0; n < 4; ++n)
            acc[m][n] = (f32x4){0.f, 0.f, 0.f, 0.f};

    const int srow = wid * 32 + (lane >> 2);
    const int kc   = (lane & 3) * 8;
    const unsigned short* Ab = A  + (size_t)(row0 + srow) * K + kc;
    const unsigned short* Bb = Bt + (size_t)(col0 + srow) * K + kc;
    unsigned short* AlB = &Al[wid * 32 * 32];
    unsigned short* BlB = &Bl[wid * 32 * 32];

    for (int kt = 0; kt < K; kt += 32) {
        __builtin_amdgcn_global_load_lds(
            (const __attribute__((address_space(1))) void*)(Ab + kt),
            (__attribute__((address_space(3))) void*)(AlB), 16, 0, 0);
        __builtin_amdgcn_global_load_lds(
            (const __attribute__((address_space(1))) void*)(Ab + kt + (size_t)16 * K),
            (__attribute__((address_space(3))) void*)(AlB + 16 * 32), 16, 0, 0);
        __builtin_amdgcn_global_load_lds(
            (const __attribute__((address_space(1))) void*)(Bb + kt),
            (__attribute__((address_space(3))) void*)(BlB), 16, 0, 0);
        __builtin_amdgcn_global_load_lds(
            (const __attribute__((address_space(1))) void*)(Bb + kt + (size_t)16 * K),
            (__attribute__((address_space(3))) void*)(BlB + 16 * 32), 16, 0, 0);
        __syncthreads();

        const int fr = lane & 15, kg = (lane >> 4) * 8;
        bf16x8 a[4], b[4];
        #pragma unroll
        for (int m = 0; m < 4; ++m)
            a[m] = *(const bf16x8*)&Al[(wr * 64 + m * 16 + fr) * 32 + kg];
        #pragma unroll
        for (int n = 0; n < 4; ++n)
            b[n] = *(const bf16x8*)&Bl[(wc * 64 + n * 16 + fr) * 32 + kg];
        #pragma unroll
        for (int m = 0; m < 4; ++m)
            #pragma unroll
            for (int n = 0; n < 4; ++n)
                acc[m][n] = __builtin_amdgcn_mfma_f32_16x16x32_bf16(a[m], b[n], acc[m][n], 0, 0, 0);
        __syncthreads();
    }

    const int fr = lane & 15, rq = lane >> 4;
    #pragma unroll
    for (int m = 0; m < 4; ++m) {
        int r0 = row0 + wr * 64 + m * 16 + rq * 4;
        #pragma unroll
        for (int n = 0; n < 4; ++n) {
            int cc = col0 + wc * 64 + n * 16 + fr;
            #pragma unroll
            for (int r = 0; r < 4; ++r)
                C[(size_t)(r0 + r) * N + cc] = acc[m][n][r];
        }
    }
}

// ---------------------------------------------------------------------------
// causal depthwise conv1d + SiLU; emits fp32 uc and hi/lo bf16 pair
__global__ __launch_bounds__(256) void conv_silu_kernel(const float* __restrict__ xz,
    const float* __restrict__ cw, const float* __restrict__ cb,
    float* __restrict__ uc, unsigned short* __restrict__ uh, unsigned short* __restrict__ ul)
{
    int idx = blockIdx.x * 256 + threadIdx.x;
    int d = idx & (DI - 1);
    int t = idx >> 11;
    int l = t & (L_ - 1);
    int b = t >> 11;
    float acc = cb[d];
    #pragma unroll
    for (int k = 0; k < DCONV; ++k) {
        int lp = l + k - (DCONV - 1);
        if (lp >= 0)
            acc = fmaf(xz[((size_t)(b * L_ + lp) << 12) + d], cw[d * DCONV + k], acc);
    }
    float s = acc / (1.0f + expf(-acc));
    uc[idx] = s;
    unsigned short h = f2bf(s);
    uh[idx] = h;
    ul[idx] = f2bf(s - bf2f(h));
}

// ---------------------------------------------------------------------------
// x_proj via MFMA, split-precision (uh+ul)@(Wh+Wl), K split 8 ways.
// One wave per block: 16 tokens x 96 cols, K-chunk 256.
__global__ __launch_bounds__(64) void xproj_mfma(
    const unsigned short* __restrict__ uh, const unsigned short* __restrict__ ul,
    const unsigned short* __restrict__ Wh, const unsigned short* __restrict__ Wl,
    float* __restrict__ part)
{
    const int lane = threadIdx.x;
    const int bid = blockIdx.x;          // 2048 = 256 mb x 8 ks
    const int ks = bid & (KSP - 1);
    const int mb = bid >> 3;
    const int row0 = mb * 16;
    const int k0 = ks * (DI / KSP);
    const int fr = lane & 15, kg = (lane >> 4) * 8;

    f32x4 acc[6];
    #pragma unroll
    for (int j = 0; j < 6; ++j) acc[j] = (f32x4){0.f, 0.f, 0.f, 0.f};

    for (int kk = 0; kk < DI / KSP; kk += 32) {
        const size_t abase = (size_t)(row0 + fr) * DI + k0 + kk + kg;
        bf16x8 ah = *(const bf16x8*)&uh[abase];
        bf16x8 al = *(const bf16x8*)&ul[abase];
        #pragma unroll
        for (int j = 0; j < 6; ++j) {
            const size_t bbase = (size_t)(j * 16 + fr) * DI + k0 + kk + kg;
            bf16x8 bh = *(const bf16x8*)&Wh[bbase];
            bf16x8 bl = *(const bf16x8*)&Wl[bbase];
            acc[j] = __builtin_amdgcn_mfma_f32_16x16x32_bf16(ah, bh, acc[j], 0, 0, 0);
            acc[j] = __builtin_amdgcn_mfma_f32_16x16x32_bf16(al, bh, acc[j], 0, 0, 0);
            acc[j] = __builtin_amdgcn_mfma_f32_16x16x32_bf16(ah, bl, acc[j], 0, 0, 0);
        }
    }
    const int rq = lane >> 4;
    #pragma unroll
    for (int j = 0; j < 6; ++j) {
        int col = j * 16 + fr;
        #pragma unroll
        for (int r = 0; r < 4; ++r) {
            int row = row0 + rq * 4 + r;
            part[((size_t)ks * NTOK + row) * XD + col] = acc[j][r];
        }
    }
}

__global__ __launch_bounds__(256) void xproj_reduce(const float* __restrict__ part,
    float* __restrict__ xdbl)
{
    int i = blockIdx.x * 256 + threadIdx.x;    // NTOK*XD = 393216
    float s = 0.f;
    #pragma unroll
    for (int ks = 0; ks < KSP; ++ks)
        s += part[(size_t)ks * ((size_t)NTOK * XD) + i];
    xdbl[i] = s;
}

// ---------------------------------------------------------------------------
// dt_proj + softplus
__global__ __launch_bounds__(256) void dtproj_kernel(const float* __restrict__ xdbl,
    const float* __restrict__ dtw, const float* __restrict__ dtb, float* __restrict__ dt)
{
    __shared__ float xl[16 * 64];
    const int tid = threadIdx.x;
    const int tokblk = blockIdx.x >> 3;
    const int dblk = blockIdx.x & 7;
    const int tok0 = tokblk * 16;
    const int d = dblk * 256 + tid;
    {
        int pos = tid * 4;
        int tr = pos >> 6, rr = pos & 63;
        *(float4*)&xl[pos] = *(const float4*)(xdbl + (size_t)(tok0 + tr) * XD + rr);
    }
    __syncthreads();
    float acc[16];
    float bias = dtb[d];
    #pragma unroll
    for (int t = 0; t < 16; ++t) acc[t] = bias;
    for (int r = 0; r < DTR; ++r) {
        float w = dtw[(size_t)r * DI + d];
        #pragma unroll
        for (int t = 0; t < 16; ++t)
            acc[t] = fmaf(xl[t * 64 + r], w, acc[t]);
    }
    #pragma unroll
    for (int t = 0; t < 16; ++t) {
        float v = acc[t];
        float sp = (v > 20.0f) ? v : log1pf(expf(v));
        dt[(size_t)(tok0 + t) * DI + d] = sp;
    }
}

// ---------------------------------------------------------------------------
// Chunked selective scan (3 passes)
__global__ __launch_bounds__(256) void scan_passA(
    const float* __restrict__ dt, const float* __restrict__ uc,
    const float* __restrict__ xdbl, const float* __restrict__ A_log,
    float* __restrict__ hA, float* __restrict__ PA)
{
    const int tid = threadIdx.x;
    const int bid = blockIdx.x;
    const int dblk = bid & 7;
    const int c = (bid >> 3) & (NCH - 1);
    const int b = bid >> 8;
    const int d = dblk * 256 + tid;
    const size_t t0 = (size_t)b * L_ + (size_t)c * CH;

    float Av[NST];
    {
        const float4* ap = (const float4*)(A_log + (size_t)d * NST);
        float4 a0 = ap[0], a1 = ap[1], a2 = ap[2], a3 = ap[3];
        Av[0]=-expf(a0.x); Av[1]=-expf(a0.y); Av[2]=-expf(a0.z); Av[3]=-expf(a0.w);
        Av[4]=-expf(a1.x); Av[5]=-expf(a1.y); Av[6]=-expf(a1.z); Av[7]=-expf(a1.w);
        Av[8]=-expf(a2.x); Av[9]=-expf(a2.y); Av[10]=-expf(a2.z); Av[11]=-expf(a2.w);
        Av[12]=-expf(a3.x); Av[13]=-expf(a3.y); Av[14]=-expf(a3.z); Av[15]=-expf(a3.w);
    }
    float h[NST], P[NST];
    #pragma unroll
    for (int n = 0; n < NST; ++n) { h[n] = 0.f; P[n] = 1.f; }

    float dtv[4], uv[4];
    float4 Bq[2][4];
    #pragma unroll
    for (int j = 0; j < 4; ++j) {
        size_t t = t0 + j;
        dtv[j] = dt[t * DI + d];
        uv[j]  = uc[t * DI + d];
    }
    #pragma unroll
    for (int j = 0; j < 2; ++j) {
        const float4* xr = (const float4*)(xdbl + (t0 + j) * XD + DTR);
        Bq[j][0] = xr[0]; Bq[j][1] = xr[1]; Bq[j][2] = xr[2]; Bq[j][3] = xr[3];
    }

    #pragma unroll 4
    for (int l = 0; l < CH; ++l) {
        const int s2 = l & 1, s4 = l & 3;
        float dtc = dtv[s4], uvc = uv[s4];
        float bc[16];
        bc[0]=Bq[s2][0].x; bc[1]=Bq[s2][0].y; bc[2]=Bq[s2][0].z; bc[3]=Bq[s2][0].w;
        bc[4]=Bq[s2][1].x; bc[5]=Bq[s2][1].y; bc[6]=Bq[s2][1].z; bc[7]=Bq[s2][1].w;
        bc[8]=Bq[s2][2].x; bc[9]=Bq[s2][2].y; bc[10]=Bq[s2][2].z; bc[11]=Bq[s2][2].w;
        bc[12]=Bq[s2][3].x; bc[13]=Bq[s2][3].y; bc[14]=Bq[s2][3].z; bc[15]=Bq[s2][3].w;
        if (l + 4 < CH) {
            size_t t = t0 + l + 4;
            dtv[s4] = dt[t * DI + d];
            uv[s4]  = uc[t * DI + d];
        }
        if (l + 2 < CH) {
            const float4* xr = (const float4*)(xdbl + (t0 + l + 2) * XD + DTR);
            Bq[s2][0] = xr[0]; Bq[s2][1] = xr[1]; Bq[s2][2] = xr[2]; Bq[s2][3] = xr[3];
        }
        float dtu = dtc * uvc;
        #pragma unroll
        for (int n = 0; n < NST; ++n) {
            float dA = expf(dtc * Av[n]);
            h[n] = fmaf(dA, h[n], dtu * bc[n]);
            P[n] *= dA;
        }
    }
    size_t obase = ((size_t)(b * NCH + c) * DI + d) * NST;
    float4* hp = (float4*)&hA[obase];
    hp[0] = make_float4(h[0], h[1], h[2], h[3]);
    hp[1] = make_float4(h[4], h[5], h[6], h[7]);
    hp[2] = make_float4(h[8], h[9], h[10], h[11]);
    hp[3] = make_float4(h[12], h[13], h[14], h[15]);
    float4* pp = (float4*)&PA[obase];
    pp[0] = make_float4(P[0], P[1], P[2], P[3]);
    pp[1] = make_float4(P[4], P[5], P[6], P[7]);
    pp[2] = make_float4(P[8], P[9], P[10], P[11]);
    pp[3] = make_float4(P[12], P[13], P[14], P[15]);
}

__global__ __launch_bounds__(256) void scan_passB(
    const float* __restrict__ hA, const float* __restrict__ PA,
    float* __restrict__ hin)
{
    int g = blockIdx.x * 256 + threadIdx.x;
    int b = g >> 15;
    int rest = g & 32767;
    float h = 0.f;
    for (int c = 0; c < NCH; ++c) {
        size_t idx = ((size_t)(b * NCH + c) * DI) * NST + rest;
        hin[idx] = h;
        h = fmaf(PA[idx], h, hA[idx]);
    }
}

__global__ __launch_bounds__(256) void scan_passC(
    const float* __restrict__ dt, const float* __restrict__ uc,
    const float* __restrict__ xdbl, const float* __restrict__ xz,
    const float* __restrict__ A_log, const float* __restrict__ Dp,
    const float* __restrict__ hin, unsigned short* __restrict__ yg)
{
    const int tid = threadIdx.x;
    const int bid = blockIdx.x;
    const int dblk = bid & 7;
    const int c = (bid >> 3) & (NCH - 1);
    const int b = bid >> 8;
    const int d = dblk * 256 + tid;
    const size_t t0 = (size_t)b * L_ + (size_t)c * CH;

    float Av[NST];
    {
        const float4* ap = (const float4*)(A_log + (size_t)d * NST);
        float4 a0 = ap[0], a1 = ap[1], a2 = ap[2], a3 = ap[3];
        Av[0]=-expf(a0.x); Av[1]=-expf(a0.y); Av[2]=-expf(a0.z); Av[3]=-expf(a0.w);
        Av[4]=-expf(a1.x); Av[5]=-expf(a1.y); Av[6]=-expf(a1.z); Av[7]=-expf(a1.w);
        Av[8]=-expf(a2.x); Av[9]=-expf(a2.y); Av[10]=-expf(a2.z); Av[11]=-expf(a2.w);
        Av[12]=-expf(a3.x); Av[13]=-expf(a3.y); Av[14]=-expf(a3.z); Av[15]=-expf(a3.w);
    }
    const float Dv = Dp[d];
    float h[NST];
    {
        size_t ibase = ((size_t)(b * NCH + c) * DI + d) * NST;
        const float4* hp = (const float4*)&hin[ibase];
        float4 h0 = hp[0], h1 = hp[1], h2 = hp[2], h3 = hp[3];
        h[0]=h0.x; h[1]=h0.y; h[2]=h0.z; h[3]=h0.w;
        h[4]=h1.x; h[5]=h1.y; h[6]=h1.z; h[7]=h1.w;
        h[8]=h2.x; h[9]=h2.y; h[10]=h2.z; h[11]=h2.w;
        h[12]=h3.x; h[13]=h3.y; h[14]=h3.z; h[15]=h3.w;
    }

    float dtv[4], uv[4], rv[4];
    float4 Bq[2][4], Cq[2][4];
    #pragma unroll
    for (int j = 0; j < 4; ++j) {
        size_t t = t0 + j;
        dtv[j] = dt[t * DI + d];
        uv[j]  = uc[t * DI + d];
        rv[j]  = xz[(t << 12) + DI + d];
    }
    #pragma unroll
    for (int j = 0; j < 2; ++j) {
        const float4* xr = (const float4*)(xdbl + (t0 + j) * XD + DTR);
        Bq[j][0] = xr[0]; Bq[j][1] = xr[1]; Bq[j][2] = xr[2]; Bq[j][3] = xr[3];
        Cq[j][0] = xr[4]; Cq[j][1] = xr[5]; Cq[j][2] = xr[6]; Cq[j][3] = xr[7];
    }

    #pragma unroll 4
    for (int l = 0; l < CH; ++l) {
        const int s2 = l & 1, s4 = l & 3;
        float dtc = dtv[s4], uvc = uv[s4], rvc = rv[s4];
        float bc[16], cc[16];
        bc[0]=Bq[s2][0].x; bc[1]=Bq[s2][0].y; bc[2]=Bq[s2][0].z; bc[3]=Bq[s2][0].w;
        bc[4]=Bq[s2][1].x; bc[5]=Bq[s2][1].y; bc[6]=Bq[s2][1].z; bc[7]=Bq[s2][1].w;
        bc[8]=Bq[s2][2].x; bc[9]=Bq[s2][2].y; bc[10]=Bq[s2][2].z; bc[11]=Bq[s2][2].w;
        bc[12]=Bq[s2][3].x; bc[13]=Bq[s2][3].y; bc[14]=Bq[s2][3].z; bc[15]=Bq[s2][3].w;
        cc[0]=Cq[s2][0].x; cc[1]=Cq[s2][0].y; cc[2]=Cq[s2][0].z; cc[3]=Cq[s2][0].w;
        cc[4]=Cq[s2][1].x; cc[5]=Cq[s2][1].y; cc[6]=Cq[s2][1].z; cc[7]=Cq[s2][1].w;
        cc[8]=Cq[s2][2].x; cc[9]=Cq[s2][2].y; cc[10]=Cq[s2][2].z; cc[11]=Cq[s2][2].w;
        cc[12]=Cq[s2][3].x; cc[13]=Cq[s2][3].y; cc[14]=Cq[s2][3].z; cc[15]=Cq[s2][3].w;
        if (l + 4 < CH) {
            size_t t = t0 + l + 4;
            dtv[s4] = dt[t * DI + d];
            uv[s4]  = uc[t * DI + d];
            rv[s4]  = xz[(t << 12) + DI + d];
        }
        if (l + 2 < CH) {
            const float4* xr = (const float4*)(xdbl + (t0 + l + 2) * XD + DTR);
            Bq[s2][0] = xr[0]; Bq[s2][1] = xr[1]; Bq[s2][2] = xr[2]; Bq[s2][3] = xr[3];
            Cq[s2][0] = xr[4]; Cq[s2][1] = xr[5]; Cq[s2][2] = xr[6]; Cq[s2][3] = xr[7];
        }
        float dtu = dtc * uvc;
        float y = 0.f;
        #pragma unroll
        for (int n = 0; n < NST; ++n) {
            float dA = expf(dtc * Av[n]);
            h[n] = fmaf(dA, h[n], dtu * bc[n]);
            y = fmaf(h[n], cc[n], y);
        }
        y = fmaf(uvc, Dv, y);
        float sig = 1.0f / (1.0f + expf(-rvc));
        yg[(t0 + l) * DI + d] = f2bf(y * rvc * sig);
    }
}

// ---------------------------------------------------------------------------
extern "C" void kernel_launch(void* const* d_in, const int* in_sizes, int n_in,
                              void* d_out, int out_size, void* d_ws, size_t ws_size,
                              hipStream_t stream)
{
    const float* x    = (const float*)d_in[0];
    const float* nw   = (const float*)d_in[1];
    const float* ipw  = (const float*)d_in[2];
    const float* cw   = (const float*)d_in[3];
    const float* cb   = (const float*)d_in[4];
    const float* xpw  = (const float*)d_in[5];
    const float* dtw  = (const float*)d_in[6];
    const float* dtb  = (const float*)d_in[7];
    const float* alog = (const float*)d_in[8];
    const float* dpar = (const float*)d_in[9];
    const float* opw  = (const float*)d_in[10];
    float* out = (float*)d_out;

    char* p = (char*)d_ws;
    float* xz    = (float*)p;  p += (size_t)NTOK * 2 * DI * 4;       // 67.1 MB
    float* uc    = (float*)p;  p += (size_t)NTOK * DI * 4;           // 33.6 MB
    float* xdbl  = (float*)p;  p += (size_t)NTOK * XD * 4;           //  1.6 MB
    float* dtbuf = (float*)p;  p += (size_t)NTOK * DI * 4;           // 33.6 MB
    float* hin   = (float*)p;  p += (size_t)B_ * NCH * DI * NST * 4; //  8.4 MB
    unsigned short* yg   = (unsigned short*)p;  p += (size_t)NTOK * DI * 2;   // 16.8 MB
    unsigned short* xnb  = (unsigned short*)p;  p += (size_t)NTOK * DM * 2;   //  8.4 MB
    unsigned short* ipwt = (unsigned short*)p;  p += (size_t)DM * 2 * DI * 2; //  8.4 MB
    unsigned short* opwt = (unsigned short*)p;  p += (size_t)DI * DM * 2;     //  4.2 MB
    unsigned short* xpwh = (unsigned short*)p;  p += (size_t)XD * DI * 2;     //  0.4 MB
    unsigned short* xpwl = (unsigned short*)p;  p += (size_t)XD * DI * 2;     //  0.4 MB
    // aliases (stream-ordered lifetimes):
    float* hA = (float*)xnb;                 // scan A out (dead after B); xnb dead after gemm1
    float* PA = (float*)ipwt;                // ipwt dead after gemm1
    unsigned short* uh = (unsigned short*)dtbuf;              // dead before dtproj writes
    unsigned short* ul = (unsigned short*)(dtbuf + (size_t)NTOK * DI / 2);
    float* part = (float*)yg;                // xproj partials; yg written later in passC

    transpose_cast<<<dim3(2 * DI / 32, DM / 32), 256, 0, stream>>>(ipw, ipwt, DM, 2 * DI);
    transpose_cast<<<dim3(DM / 32, DI / 32), 256, 0, stream>>>(opw, opwt, DI, DM);
    transpose_cast_hl<<<dim3(XD / 32, DI / 32), 256, 0, stream>>>(xpw, xpwh, xpwl, DI, XD);

    rmsnorm_bf16<<<NTOK, 256, 0, stream>>>(x, nw, xnb);

    gemm_bf16t<<<dim3(2 * DI / 128, NTOK / 128), 256, 0, stream>>>(xnb, ipwt, xz, NTOK, 2 * DI, DM);

    conv_silu_kernel<<<NTOK * DI / 256, 256, 0, stream>>>(xz, cw, cb, uc, uh, ul);

    xproj_mfma<<<(NTOK / 16) * KSP, 64, 0, stream>>>(uh, ul, xpwh, xpwl, part);
    xproj_reduce<<<NTOK * XD / 256, 256, 0, stream>>>(part, xdbl);

    dtproj_kernel<<<(NTOK / 16) * (DI / 256), 256, 0, stream>>>(xdbl, dtw, dtb, dtbuf);

    scan_passA<<<B_ * NCH * (DI / 256), 256, 0, stream>>>(dtbuf, uc, xdbl, alog, hA, PA);
    scan_passB<<<B_ * DI * NST / 256, 256, 0, stream>>>(hA, PA, hin);
    scan_passC<<<B_ * NCH * (DI / 256), 256, 0, stream>>>(dtbuf, uc, xdbl, xz, alog, dpar, hin, yg);

    gemm_bf16t<<<dim3(DM / 128, NTOK / 128), 256, 0, stream>>>(yg, opwt, out, NTOK, DM, DI);
}

// Round 8
// 462.932 us; speedup vs baseline: 4.3401x; 1.2143x over previous
//
#include <hip/hip_runtime.h>
#include <hip/hip_bf16.h>
#include <math.h>

#define B_    2
#define L_    2048
#define DM    1024
#define DI    2048
#define NTOK  (B_*L_)     /* 4096 */
#define NST   16
#define DTR   64
#define XD    96          /* DTR + 2*NST */
#define DCONV 4
#define EPS   1e-5f
#define CH    64          /* scan chunk length */
#define NCH   (L_/CH)     /* 32 */
#define KSP   8           /* xproj K-split */

typedef __attribute__((ext_vector_type(8))) short bf16x8;
typedef __attribute__((ext_vector_type(4))) float f32x4;

__device__ __forceinline__ unsigned short f2bf(float f) {
    union { float f; unsigned int u; } v; v.f = f;
    unsigned int r = v.u + 0x7fffu + ((v.u >> 16) & 1u);
    return (unsigned short)(r >> 16);
}
__device__ __forceinline__ float bf2f(unsigned short h) {
    union { unsigned int u; float f; } v; v.u = ((unsigned int)h) << 16;
    return v.f;
}

// ---------------------------------------------------------------------------
// RMSNorm -> bf16
__global__ __launch_bounds__(256) void rmsnorm_bf16(const float* __restrict__ x,
    const float* __restrict__ nw, unsigned short* __restrict__ xn)
{
    const int row = blockIdx.x;
    const int tid = threadIdx.x;
    const float* xr = x + (size_t)row * DM;
    float4 v = *(const float4*)(xr + tid * 4);
    float s = v.x*v.x + v.y*v.y + v.z*v.z + v.w*v.w;
    #pragma unroll
    for (int m = 1; m < 64; m <<= 1) s += __shfl_xor(s, m);
    __shared__ float wsum[4];
    if ((tid & 63) == 0) wsum[tid >> 6] = s;
    __syncthreads();
    float tot = wsum[0] + wsum[1] + wsum[2] + wsum[3];
    float rs = rsqrtf(tot * (1.0f / DM) + EPS);
    float4 w = *(const float4*)(nw + tid * 4);
    ushort4 o;
    o.x = f2bf(v.x*rs*w.x); o.y = f2bf(v.y*rs*w.y);
    o.z = f2bf(v.z*rs*w.z); o.w = f2bf(v.w*rs*w.w);
    *(ushort4*)(xn + (size_t)row * DM + tid * 4) = o;
}

// ---------------------------------------------------------------------------
// Transpose + cast: W[K][N] fp32 -> Wt[N][K] bf16
__global__ __launch_bounds__(256) void transpose_cast(const float* __restrict__ W,
    unsigned short* __restrict__ Wt, int K, int N)
{
    __shared__ float tile[32][33];
    const int tid = threadIdx.x;
    const int k0 = blockIdx.y * 32;
    const int n0 = blockIdx.x * 32;
    #pragma unroll
    for (int p = 0; p < 4; ++p) {
        int idx = p * 256 + tid;
        int r = idx >> 5, c = idx & 31;
        tile[c][r] = W[(size_t)(k0 + r) * N + n0 + c];
    }
    __syncthreads();
    #pragma unroll
    for (int p = 0; p < 4; ++p) {
        int idx = p * 256 + tid;
        int r = idx >> 5, c = idx & 31;
        Wt[(size_t)(n0 + r) * K + k0 + c] = f2bf(tile[r][c]);
    }
}

// Transpose + hi/lo split-cast: W[K][96] fp32 -> Wh/Wl[96][K] bf16
__global__ __launch_bounds__(256) void transpose_cast_hl(const float* __restrict__ W,
    unsigned short* __restrict__ Wh, unsigned short* __restrict__ Wl, int K, int N)
{
    __shared__ float tile[32][33];
    const int tid = threadIdx.x;
    const int k0 = blockIdx.y * 32;
    const int n0 = blockIdx.x * 32;
    #pragma unroll
    for (int p = 0; p < 4; ++p) {
        int idx = p * 256 + tid;
        int r = idx >> 5, c = idx & 31;
        tile[c][r] = W[(size_t)(k0 + r) * N + n0 + c];
    }
    __syncthreads();
    #pragma unroll
    for (int p = 0; p < 4; ++p) {
        int idx = p * 256 + tid;
        int r = idx >> 5, c = idx & 31;
        float v = tile[r][c];
        unsigned short h = f2bf(v);
        float lo = v - bf2f(h);
        size_t o = (size_t)(n0 + r) * K + k0 + c;
        Wh[o] = h;
        Wl[o] = f2bf(lo);
    }
}

// ---------------------------------------------------------------------------
// bf16 MFMA GEMM (m97 structure), 128x128 tile, BK=32
__global__ __launch_bounds__(256) void gemm_bf16t(
    const unsigned short* __restrict__ A, const unsigned short* __restrict__ Bt,
    float* __restrict__ C, int M, int N, int K)
{
    __shared__ unsigned short Al[128 * 32];
    __shared__ unsigned short Bl[128 * 32];
    const int tid  = threadIdx.x;
    const int lane = tid & 63;
    const int wid  = tid >> 6;
    const int wr = wid >> 1, wc = wid & 1;
    const int row0 = blockIdx.y * 128;
    const int col0 = blockIdx.x * 128;

    f32x4 acc[4][4];
    #pragma unroll
    for (int m = 0; m < 4; ++m)
        #pragma unroll
        for (int n = 0; n < 4; ++n)
            acc[m][n] = (f32x4){0.f, 0.f, 0.f, 0.f};

    const int srow = wid * 32 + (lane >> 2);
    const int kc   = (lane & 3) * 8;
    const unsigned short* Ab = A  + (size_t)(row0 + srow) * K + kc;
    const unsigned short* Bb = Bt + (size_t)(col0 + srow) * K + kc;
    unsigned short* AlB = &Al[wid * 32 * 32];
    unsigned short* BlB = &Bl[wid * 32 * 32];

    for (int kt = 0; kt < K; kt += 32) {
        __builtin_amdgcn_global_load_lds(
            (const __attribute__((address_space(1))) void*)(Ab + kt),
            (__attribute__((address_space(3))) void*)(AlB), 16, 0, 0);
        __builtin_amdgcn_global_load_lds(
            (const __attribute__((address_space(1))) void*)(Ab + kt + (size_t)16 * K),
            (__attribute__((address_space(3))) void*)(AlB + 16 * 32), 16, 0, 0);
        __builtin_amdgcn_global_load_lds(
            (const __attribute__((address_space(1))) void*)(Bb + kt),
            (__attribute__((address_space(3))) void*)(BlB), 16, 0, 0);
        __builtin_amdgcn_global_load_lds(
            (const __attribute__((address_space(1))) void*)(Bb + kt + (size_t)16 * K),
            (__attribute__((address_space(3))) void*)(BlB + 16 * 32), 16, 0, 0);
        __syncthreads();

        const int fr = lane & 15, kg = (lane >> 4) * 8;
        bf16x8 a[4], b[4];
        #pragma unroll
        for (int m = 0; m < 4; ++m)
            a[m] = *(const bf16x8*)&Al[(wr * 64 + m * 16 + fr) * 32 + kg];
        #pragma unroll
        for (int n = 0; n < 4; ++n)
            b[n] = *(const bf16x8*)&Bl[(wc * 64 + n * 16 + fr) * 32 + kg];
        #pragma unroll
        for (int m = 0; m < 4; ++m)
            #pragma unroll
            for (int n = 0; n < 4; ++n)
                acc[m][n] = __builtin_amdgcn_mfma_f32_16x16x32_bf16(a[m], b[n], acc[m][n], 0, 0, 0);
        __syncthreads();
    }

    const int fr = lane & 15, rq = lane >> 4;
    #pragma unroll
    for (int m = 0; m < 4; ++m) {
        int r0 = row0 + wr * 64 + m * 16 + rq * 4;
        #pragma unroll
        for (int n = 0; n < 4; ++n) {
            int cc = col0 + wc * 64 + n * 16 + fr;
            #pragma unroll
            for (int r = 0; r < 4; ++r)
                C[(size_t)(r0 + r) * N + cc] = acc[m][n][r];
        }
    }
}

// ---------------------------------------------------------------------------
// causal depthwise conv1d + SiLU; emits fp32 uc and hi/lo bf16 pair
__global__ __launch_bounds__(256) void conv_silu_kernel(const float* __restrict__ xz,
    const float* __restrict__ cw, const float* __restrict__ cb,
    float* __restrict__ uc, unsigned short* __restrict__ uh, unsigned short* __restrict__ ul)
{
    int idx = blockIdx.x * 256 + threadIdx.x;
    int d = idx & (DI - 1);
    int t = idx >> 11;
    int l = t & (L_ - 1);
    int b = t >> 11;
    float acc = cb[d];
    #pragma unroll
    for (int k = 0; k < DCONV; ++k) {
        int lp = l + k - (DCONV - 1);
        if (lp >= 0)
            acc = fmaf(xz[((size_t)(b * L_ + lp) << 12) + d], cw[d * DCONV + k], acc);
    }
    float s = acc / (1.0f + expf(-acc));
    uc[idx] = s;
    unsigned short h = f2bf(s);
    uh[idx] = h;
    ul[idx] = f2bf(s - bf2f(h));
}

// ---------------------------------------------------------------------------
// x_proj via MFMA, split-precision (uh+ul)@(Wh+Wl), K split 8 ways.
__global__ __launch_bounds__(64) void xproj_mfma(
    const unsigned short* __restrict__ uh, const unsigned short* __restrict__ ul,
    const unsigned short* __restrict__ Wh, const unsigned short* __restrict__ Wl,
    float* __restrict__ part)
{
    const int lane = threadIdx.x;
    const int bid = blockIdx.x;          // 2048 = 256 mb x 8 ks
    const int ks = bid & (KSP - 1);
    const int mb = bid >> 3;
    const int row0 = mb * 16;
    const int k0 = ks * (DI / KSP);
    const int fr = lane & 15, kg = (lane >> 4) * 8;

    f32x4 acc[6];
    #pragma unroll
    for (int j = 0; j < 6; ++j) acc[j] = (f32x4){0.f, 0.f, 0.f, 0.f};

    for (int kk = 0; kk < DI / KSP; kk += 32) {
        const size_t abase = (size_t)(row0 + fr) * DI + k0 + kk + kg;
        bf16x8 ah = *(const bf16x8*)&uh[abase];
        bf16x8 al = *(const bf16x8*)&ul[abase];
        #pragma unroll
        for (int j = 0; j < 6; ++j) {
            const size_t bbase = (size_t)(j * 16 + fr) * DI + k0 + kk + kg;
            bf16x8 bh = *(const bf16x8*)&Wh[bbase];
            bf16x8 bl = *(const bf16x8*)&Wl[bbase];
            acc[j] = __builtin_amdgcn_mfma_f32_16x16x32_bf16(ah, bh, acc[j], 0, 0, 0);
            acc[j] = __builtin_amdgcn_mfma_f32_16x16x32_bf16(al, bh, acc[j], 0, 0, 0);
            acc[j] = __builtin_amdgcn_mfma_f32_16x16x32_bf16(ah, bl, acc[j], 0, 0, 0);
        }
    }
    const int rq = lane >> 4;
    #pragma unroll
    for (int j = 0; j < 6; ++j) {
        int col = j * 16 + fr;
        #pragma unroll
        for (int r = 0; r < 4; ++r) {
            int row = row0 + rq * 4 + r;
            part[((size_t)ks * NTOK + row) * XD + col] = acc[j][r];
        }
    }
}

__global__ __launch_bounds__(256) void xproj_reduce(const float* __restrict__ part,
    float* __restrict__ xdbl)
{
    int i = blockIdx.x * 256 + threadIdx.x;    // NTOK*XD = 393216
    float s = 0.f;
    #pragma unroll
    for (int ks = 0; ks < KSP; ++ks)
        s += part[(size_t)ks * ((size_t)NTOK * XD) + i];
    xdbl[i] = s;
}

// ---------------------------------------------------------------------------
// dt_proj + softplus
__global__ __launch_bounds__(256) void dtproj_kernel(const float* __restrict__ xdbl,
    const float* __restrict__ dtw, const float* __restrict__ dtb, float* __restrict__ dt)
{
    __shared__ float xl[16 * 64];
    const int tid = threadIdx.x;
    const int tokblk = blockIdx.x >> 3;
    const int dblk = blockIdx.x & 7;
    const int tok0 = tokblk * 16;
    const int d = dblk * 256 + tid;
    {
        int pos = tid * 4;
        int tr = pos >> 6, rr = pos & 63;
        *(float4*)&xl[pos] = *(const float4*)(xdbl + (size_t)(tok0 + tr) * XD + rr);
    }
    __syncthreads();
    float acc[16];
    float bias = dtb[d];
    #pragma unroll
    for (int t = 0; t < 16; ++t) acc[t] = bias;
    for (int r = 0; r < DTR; ++r) {
        float w = dtw[(size_t)r * DI + d];
        #pragma unroll
        for (int t = 0; t < 16; ++t)
            acc[t] = fmaf(xl[t * 64 + r], w, acc[t]);
    }
    #pragma unroll
    for (int t = 0; t < 16; ++t) {
        float v = acc[t];
        float sp = (v > 20.0f) ? v : log1pf(expf(v));
        dt[(size_t)(tok0 + t) * DI + d] = sp;
    }
}

// ---------------------------------------------------------------------------
// Chunked selective scan (3 passes).  R8: n-split 2x (8 states/thread) +
// __expf fast intrinsic.  Thread = (d, half); grid = B*NCH*(DI/128).
__global__ __launch_bounds__(256) void scan_passA(
    const float* __restrict__ dt, const float* __restrict__ uc,
    const float* __restrict__ xdbl, const float* __restrict__ A_log,
    float* __restrict__ hA, float* __restrict__ PA)
{
    const int tid = threadIdx.x;
    const int bid = blockIdx.x;            // 1024 = B * NCH * 16
    const int dblk = bid & 15;
    const int c = (bid >> 4) & (NCH - 1);
    const int b = bid >> 9;
    const int di = tid >> 1, hf = tid & 1;
    const int d = dblk * 128 + di;
    const size_t t0 = (size_t)b * L_ + (size_t)c * CH;

    float Av[8];
    {
        const float4* ap = (const float4*)(A_log + (size_t)d * NST + hf * 8);
        float4 a0 = ap[0], a1 = ap[1];
        Av[0]=-expf(a0.x); Av[1]=-expf(a0.y); Av[2]=-expf(a0.z); Av[3]=-expf(a0.w);
        Av[4]=-expf(a1.x); Av[5]=-expf(a1.y); Av[6]=-expf(a1.z); Av[7]=-expf(a1.w);
    }
    float h[8], P[8];
    #pragma unroll
    for (int n = 0; n < 8; ++n) { h[n] = 0.f; P[n] = 1.f; }

    float dtv[4], uv[4];
    float4 Bq[2][2];
    #pragma unroll
    for (int j = 0; j < 4; ++j) {
        size_t t = t0 + j;
        dtv[j] = dt[t * DI + d];
        uv[j]  = uc[t * DI + d];
    }
    #pragma unroll
    for (int j = 0; j < 2; ++j) {
        const float4* xr = (const float4*)(xdbl + (t0 + j) * XD + DTR + hf * 8);
        Bq[j][0] = xr[0]; Bq[j][1] = xr[1];
    }

    #pragma unroll 4
    for (int l = 0; l < CH; ++l) {
        const int s2 = l & 1, s4 = l & 3;
        float dtc = dtv[s4], uvc = uv[s4];
        float bc[8];
        bc[0]=Bq[s2][0].x; bc[1]=Bq[s2][0].y; bc[2]=Bq[s2][0].z; bc[3]=Bq[s2][0].w;
        bc[4]=Bq[s2][1].x; bc[5]=Bq[s2][1].y; bc[6]=Bq[s2][1].z; bc[7]=Bq[s2][1].w;
        if (l + 4 < CH) {
            size_t t = t0 + l + 4;
            dtv[s4] = dt[t * DI + d];
            uv[s4]  = uc[t * DI + d];
        }
        if (l + 2 < CH) {
            const float4* xr = (const float4*)(xdbl + (t0 + l + 2) * XD + DTR + hf * 8);
            Bq[s2][0] = xr[0]; Bq[s2][1] = xr[1];
        }
        float dtu = dtc * uvc;
        #pragma unroll
        for (int n = 0; n < 8; ++n) {
            float dA = __expf(dtc * Av[n]);
            h[n] = fmaf(dA, h[n], dtu * bc[n]);
            P[n] *= dA;
        }
    }
    size_t obase = ((size_t)(b * NCH + c) * DI + d) * NST + hf * 8;
    float4* hp = (float4*)&hA[obase];
    hp[0] = make_float4(h[0], h[1], h[2], h[3]);
    hp[1] = make_float4(h[4], h[5], h[6], h[7]);
    float4* pp = (float4*)&PA[obase];
    pp[0] = make_float4(P[0], P[1], P[2], P[3]);
    pp[1] = make_float4(P[4], P[5], P[6], P[7]);
}

__global__ __launch_bounds__(256) void scan_passB(
    const float* __restrict__ hA, const float* __restrict__ PA,
    float* __restrict__ hin)
{
    int g = blockIdx.x * 256 + threadIdx.x;
    int b = g >> 15;
    int rest = g & 32767;
    float h = 0.f;
    for (int c = 0; c < NCH; ++c) {
        size_t idx = ((size_t)(b * NCH + c) * DI) * NST + rest;
        hin[idx] = h;
        h = fmaf(PA[idx], h, hA[idx]);
    }
}

__global__ __launch_bounds__(256) void scan_passC(
    const float* __restrict__ dt, const float* __restrict__ uc,
    const float* __restrict__ xdbl, const float* __restrict__ xz,
    const float* __restrict__ A_log, const float* __restrict__ Dp,
    const float* __restrict__ hin, unsigned short* __restrict__ yg)
{
    const int tid = threadIdx.x;
    const int bid = blockIdx.x;            // 1024 = B * NCH * 16
    const int dblk = bid & 15;
    const int c = (bid >> 4) & (NCH - 1);
    const int b = bid >> 9;
    const int di = tid >> 1, hf = tid & 1;
    const int d = dblk * 128 + di;
    const size_t t0 = (size_t)b * L_ + (size_t)c * CH;

    float Av[8];
    {
        const float4* ap = (const float4*)(A_log + (size_t)d * NST + hf * 8);
        float4 a0 = ap[0], a1 = ap[1];
        Av[0]=-expf(a0.x); Av[1]=-expf(a0.y); Av[2]=-expf(a0.z); Av[3]=-expf(a0.w);
        Av[4]=-expf(a1.x); Av[5]=-expf(a1.y); Av[6]=-expf(a1.z); Av[7]=-expf(a1.w);
    }
    const float Dv = Dp[d];
    float h[8];
    {
        size_t ibase = ((size_t)(b * NCH + c) * DI + d) * NST + hf * 8;
        const float4* hp = (const float4*)&hin[ibase];
        float4 h0 = hp[0], h1 = hp[1];
        h[0]=h0.x; h[1]=h0.y; h[2]=h0.z; h[3]=h0.w;
        h[4]=h1.x; h[5]=h1.y; h[6]=h1.z; h[7]=h1.w;
    }

    float dtv[4], uv[4], rv[4];
    float4 Bq[2][2], Cq[2][2];
    #pragma unroll
    for (int j = 0; j < 4; ++j) {
        size_t t = t0 + j;
        dtv[j] = dt[t * DI + d];
        uv[j]  = uc[t * DI + d];
        rv[j]  = xz[(t << 12) + DI + d];
    }
    #pragma unroll
    for (int j = 0; j < 2; ++j) {
        const float4* xr = (const float4*)(xdbl + (t0 + j) * XD + DTR + hf * 8);
        Bq[j][0] = xr[0]; Bq[j][1] = xr[1];
        Cq[j][0] = xr[4]; Cq[j][1] = xr[5];   // C is 16 floats after B
    }

    #pragma unroll 4
    for (int l = 0; l < CH; ++l) {
        const int s2 = l & 1, s4 = l & 3;
        float dtc = dtv[s4], uvc = uv[s4], rvc = rv[s4];
        float bc[8], cc[8];
        bc[0]=Bq[s2][0].x; bc[1]=Bq[s2][0].y; bc[2]=Bq[s2][0].z; bc[3]=Bq[s2][0].w;
        bc[4]=Bq[s2][1].x; bc[5]=Bq[s2][1].y; bc[6]=Bq[s2][1].z; bc[7]=Bq[s2][1].w;
        cc[0]=Cq[s2][0].x; cc[1]=Cq[s2][0].y; cc[2]=Cq[s2][0].z; cc[3]=Cq[s2][0].w;
        cc[4]=Cq[s2][1].x; cc[5]=Cq[s2][1].y; cc[6]=Cq[s2][1].z; cc[7]=Cq[s2][1].w;
        if (l + 4 < CH) {
            size_t t = t0 + l + 4;
            dtv[s4] = dt[t * DI + d];
            uv[s4]  = uc[t * DI + d];
            rv[s4]  = xz[(t << 12) + DI + d];
        }
        if (l + 2 < CH) {
            const float4* xr = (const float4*)(xdbl + (t0 + l + 2) * XD + DTR + hf * 8);
            Bq[s2][0] = xr[0]; Bq[s2][1] = xr[1];
            Cq[s2][0] = xr[4]; Cq[s2][1] = xr[5];
        }
        float dtu = dtc * uvc;
        float p = 0.f;
        #pragma unroll
        for (int n = 0; n < 8; ++n) {
            float dA = __expf(dtc * Av[n]);
            h[n] = fmaf(dA, h[n], dtu * bc[n]);
            p = fmaf(h[n], cc[n], p);
        }
        p += __shfl_xor(p, 1);
        if (hf == 0) {
            float y = fmaf(uvc, Dv, p);
            float sig = 1.0f / (1.0f + __expf(-rvc));
            yg[(t0 + l) * DI + d] = f2bf(y * rvc * sig);
        }
    }
}

// ---------------------------------------------------------------------------
extern "C" void kernel_launch(void* const* d_in, const int* in_sizes, int n_in,
                              void* d_out, int out_size, void* d_ws, size_t ws_size,
                              hipStream_t stream)
{
    const float* x    = (const float*)d_in[0];
    const float* nw   = (const float*)d_in[1];
    const float* ipw  = (const float*)d_in[2];
    const float* cw   = (const float*)d_in[3];
    const float* cb   = (const float*)d_in[4];
    const float* xpw  = (const float*)d_in[5];
    const float* dtw  = (const float*)d_in[6];
    const float* dtb  = (const float*)d_in[7];
    const float* alog = (const float*)d_in[8];
    const float* dpar = (const float*)d_in[9];
    const float* opw  = (const float*)d_in[10];
    float* out = (float*)d_out;

    char* p = (char*)d_ws;
    float* xz    = (float*)p;  p += (size_t)NTOK * 2 * DI * 4;       // 67.1 MB
    float* uc    = (float*)p;  p += (size_t)NTOK * DI * 4;           // 33.6 MB
    float* xdbl  = (float*)p;  p += (size_t)NTOK * XD * 4;           //  1.6 MB
    float* dtbuf = (float*)p;  p += (size_t)NTOK * DI * 4;           // 33.6 MB
    float* hin   = (float*)p;  p += (size_t)B_ * NCH * DI * NST * 4; //  8.4 MB
    unsigned short* yg   = (unsigned short*)p;  p += (size_t)NTOK * DI * 2;   // 16.8 MB
    unsigned short* xnb  = (unsigned short*)p;  p += (size_t)NTOK * DM * 2;   //  8.4 MB
    unsigned short* ipwt = (unsigned short*)p;  p += (size_t)DM * 2 * DI * 2; //  8.4 MB
    unsigned short* opwt = (unsigned short*)p;  p += (size_t)DI * DM * 2;     //  4.2 MB
    unsigned short* xpwh = (unsigned short*)p;  p += (size_t)XD * DI * 2;     //  0.4 MB
    unsigned short* xpwl = (unsigned short*)p;  p += (size_t)XD * DI * 2;     //  0.4 MB
    // aliases (stream-ordered lifetimes):
    float* hA = (float*)xnb;                 // scan A out (dead after B); xnb dead after gemm1
    float* PA = (float*)ipwt;                // ipwt dead after gemm1
    unsigned short* uh = (unsigned short*)dtbuf;              // dead before dtproj writes
    unsigned short* ul = (unsigned short*)(dtbuf + (size_t)NTOK * DI / 2);
    float* part = (float*)yg;                // xproj partials; yg written later in passC

    transpose_cast<<<dim3(2 * DI / 32, DM / 32), 256, 0, stream>>>(ipw, ipwt, DM, 2 * DI);
    transpose_cast<<<dim3(DM / 32, DI / 32), 256, 0, stream>>>(opw, opwt, DI, DM);
    transpose_cast_hl<<<dim3(XD / 32, DI / 32), 256, 0, stream>>>(xpw, xpwh, xpwl, DI, XD);

    rmsnorm_bf16<<<NTOK, 256, 0, stream>>>(x, nw, xnb);

    gemm_bf16t<<<dim3(2 * DI / 128, NTOK / 128), 256, 0, stream>>>(xnb, ipwt, xz, NTOK, 2 * DI, DM);

    conv_silu_kernel<<<NTOK * DI / 256, 256, 0, stream>>>(xz, cw, cb, uc, uh, ul);

    xproj_mfma<<<(NTOK / 16) * KSP, 64, 0, stream>>>(uh, ul, xpwh, xpwl, part);
    xproj_reduce<<<NTOK * XD / 256, 256, 0, stream>>>(part, xdbl);

    dtproj_kernel<<<(NTOK / 16) * (DI / 256), 256, 0, stream>>>(xdbl, dtw, dtb, dtbuf);

    scan_passA<<<B_ * NCH * (DI / 128), 256, 0, stream>>>(dtbuf, uc, xdbl, alog, hA, PA);
    scan_passB<<<B_ * DI * NST / 256, 256, 0, stream>>>(hA, PA, hin);
    scan_passC<<<B_ * NCH * (DI / 128), 256, 0, stream>>>(dtbuf, uc, xdbl, xz, alog, dpar, hin, yg);

    gemm_bf16t<<<dim3(DM / 128, NTOK / 128), 256, 0, stream>>>(yg, opwt, out, NTOK, DM, DI);
}

// Round 9
// 419.573 us; speedup vs baseline: 4.7886x; 1.1033x over previous
//
#include <hip/hip_runtime.h>
#include <hip/hip_bf16.h>
#include <math.h>

#define B_    2
#define L_    2048
#define DM    1024
#define DI    2048
#define NTOK  (B_*L_)     /* 4096 */
#define NST   16
#define DTR   64
#define XD    96          /* DTR + 2*NST */
#define DCONV 4
#define EPS   1e-5f
#define CH    64          /* scan chunk length */
#define NCH   (L_/CH)     /* 32 */
#define KSP   8           /* xproj K-split */

typedef __attribute__((ext_vector_type(8))) short bf16x8;
typedef __attribute__((ext_vector_type(4))) float f32x4;

__device__ __forceinline__ unsigned short f2bf(float f) {
    union { float f; unsigned int u; } v; v.f = f;
    unsigned int r = v.u + 0x7fffu + ((v.u >> 16) & 1u);
    return (unsigned short)(r >> 16);
}
__device__ __forceinline__ float bf2f(unsigned short h) {
    union { unsigned int u; float f; } v; v.u = ((unsigned int)h) << 16;
    return v.f;
}

// ---------------------------------------------------------------------------
// RMSNorm -> bf16
__global__ __launch_bounds__(256) void rmsnorm_bf16(const float* __restrict__ x,
    const float* __restrict__ nw, unsigned short* __restrict__ xn)
{
    const int row = blockIdx.x;
    const int tid = threadIdx.x;
    const float* xr = x + (size_t)row * DM;
    float4 v = *(const float4*)(xr + tid * 4);
    float s = v.x*v.x + v.y*v.y + v.z*v.z + v.w*v.w;
    #pragma unroll
    for (int m = 1; m < 64; m <<= 1) s += __shfl_xor(s, m);
    __shared__ float wsum[4];
    if ((tid & 63) == 0) wsum[tid >> 6] = s;
    __syncthreads();
    float tot = wsum[0] + wsum[1] + wsum[2] + wsum[3];
    float rs = rsqrtf(tot * (1.0f / DM) + EPS);
    float4 w = *(const float4*)(nw + tid * 4);
    ushort4 o;
    o.x = f2bf(v.x*rs*w.x); o.y = f2bf(v.y*rs*w.y);
    o.z = f2bf(v.z*rs*w.z); o.w = f2bf(v.w*rs*w.w);
    *(ushort4*)(xn + (size_t)row * DM + tid * 4) = o;
}

// ---------------------------------------------------------------------------
// Transpose + cast: W[K][N] fp32 -> Wt[N][K] bf16
__global__ __launch_bounds__(256) void transpose_cast(const float* __restrict__ W,
    unsigned short* __restrict__ Wt, int K, int N)
{
    __shared__ float tile[32][33];
    const int tid = threadIdx.x;
    const int k0 = blockIdx.y * 32;
    const int n0 = blockIdx.x * 32;
    #pragma unroll
    for (int p = 0; p < 4; ++p) {
        int idx = p * 256 + tid;
        int r = idx >> 5, c = idx & 31;
        tile[c][r] = W[(size_t)(k0 + r) * N + n0 + c];
    }
    __syncthreads();
    #pragma unroll
    for (int p = 0; p < 4; ++p) {
        int idx = p * 256 + tid;
        int r = idx >> 5, c = idx & 31;
        Wt[(size_t)(n0 + r) * K + k0 + c] = f2bf(tile[r][c]);
    }
}

// Transpose + hi/lo split-cast: W[K][N] fp32 -> Wh/Wl[N][K] bf16
__global__ __launch_bounds__(256) void transpose_cast_hl(const float* __restrict__ W,
    unsigned short* __restrict__ Wh, unsigned short* __restrict__ Wl, int K, int N)
{
    __shared__ float tile[32][33];
    const int tid = threadIdx.x;
    const int k0 = blockIdx.y * 32;
    const int n0 = blockIdx.x * 32;
    #pragma unroll
    for (int p = 0; p < 4; ++p) {
        int idx = p * 256 + tid;
        int r = idx >> 5, c = idx & 31;
        tile[c][r] = W[(size_t)(k0 + r) * N + n0 + c];
    }
    __syncthreads();
    #pragma unroll
    for (int p = 0; p < 4; ++p) {
        int idx = p * 256 + tid;
        int r = idx >> 5, c = idx & 31;
        float v = tile[r][c];
        unsigned short h = f2bf(v);
        float lo = v - bf2f(h);
        size_t o = (size_t)(n0 + r) * K + k0 + c;
        Wh[o] = h;
        Wl[o] = f2bf(lo);
    }
}

// ---------------------------------------------------------------------------
// bf16 MFMA GEMM (m97 structure), 128x128 tile, BK=32
__global__ __launch_bounds__(256) void gemm_bf16t(
    const unsigned short* __restrict__ A, const unsigned short* __restrict__ Bt,
    float* __restrict__ C, int M, int N, int K)
{
    __shared__ unsigned short Al[128 * 32];
    __shared__ unsigned short Bl[128 * 32];
    const int tid  = threadIdx.x;
    const int lane = tid & 63;
    const int wid  = tid >> 6;
    const int wr = wid >> 1, wc = wid & 1;
    const int row0 = blockIdx.y * 128;
    const int col0 = blockIdx.x * 128;

    f32x4 acc[4][4];
    #pragma unroll
    for (int m = 0; m < 4; ++m)
        #pragma unroll
        for (int n = 0; n < 4; ++n)
            acc[m][n] = (f32x4){0.f, 0.f, 0.f, 0.f};

    const int srow = wid * 32 + (lane >> 2);
    const int kc   = (lane & 3) * 8;
    const unsigned short* Ab = A  + (size_t)(row0 + srow) * K + kc;
    const unsigned short* Bb = Bt + (size_t)(col0 + srow) * K + kc;
    unsigned short* AlB = &Al[wid * 32 * 32];
    unsigned short* BlB = &Bl[wid * 32 * 32];

    for (int kt = 0; kt < K; kt += 32) {
        __builtin_amdgcn_global_load_lds(
            (const __attribute__((address_space(1))) void*)(Ab + kt),
            (__attribute__((address_space(3))) void*)(AlB), 16, 0, 0);
        __builtin_amdgcn_global_load_lds(
            (const __attribute__((address_space(1))) void*)(Ab + kt + (size_t)16 * K),
            (__attribute__((address_space(3))) void*)(AlB + 16 * 32), 16, 0, 0);
        __builtin_amdgcn_global_load_lds(
            (const __attribute__((address_space(1))) void*)(Bb + kt),
            (__attribute__((address_space(3))) void*)(BlB), 16, 0, 0);
        __builtin_amdgcn_global_load_lds(
            (const __attribute__((address_space(1))) void*)(Bb + kt + (size_t)16 * K),
            (__attribute__((address_space(3))) void*)(BlB + 16 * 32), 16, 0, 0);
        __syncthreads();

        const int fr = lane & 15, kg = (lane >> 4) * 8;
        bf16x8 a[4], b[4];
        #pragma unroll
        for (int m = 0; m < 4; ++m)
            a[m] = *(const bf16x8*)&Al[(wr * 64 + m * 16 + fr) * 32 + kg];
        #pragma unroll
        for (int n = 0; n < 4; ++n)
            b[n] = *(const bf16x8*)&Bl[(wc * 64 + n * 16 + fr) * 32 + kg];
        #pragma unroll
        for (int m = 0; m < 4; ++m)
            #pragma unroll
            for (int n = 0; n < 4; ++n)
                acc[m][n] = __builtin_amdgcn_mfma_f32_16x16x32_bf16(a[m], b[n], acc[m][n], 0, 0, 0);
        __syncthreads();
    }

    const int fr = lane & 15, rq = lane >> 4;
    #pragma unroll
    for (int m = 0; m < 4; ++m) {
        int r0 = row0 + wr * 64 + m * 16 + rq * 4;
        #pragma unroll
        for (int n = 0; n < 4; ++n) {
            int cc = col0 + wc * 64 + n * 16 + fr;
            #pragma unroll
            for (int r = 0; r < 4; ++r)
                C[(size_t)(r0 + r) * N + cc] = acc[m][n][r];
        }
    }
}

// ---------------------------------------------------------------------------
// causal depthwise conv1d + SiLU; emits fp32 uc and hi/lo bf16 pair
__global__ __launch_bounds__(256) void conv_silu_kernel(const float* __restrict__ xz,
    const float* __restrict__ cw, const float* __restrict__ cb,
    float* __restrict__ uc, unsigned short* __restrict__ uh, unsigned short* __restrict__ ul)
{
    int idx = blockIdx.x * 256 + threadIdx.x;
    int d = idx & (DI - 1);
    int t = idx >> 11;
    int l = t & (L_ - 1);
    int b = t >> 11;
    float acc = cb[d];
    #pragma unroll
    for (int k = 0; k < DCONV; ++k) {
        int lp = l + k - (DCONV - 1);
        if (lp >= 0)
            acc = fmaf(xz[((size_t)(b * L_ + lp) << 12) + d], cw[d * DCONV + k], acc);
    }
    float s = acc / (1.0f + expf(-acc));
    uc[idx] = s;
    unsigned short h = f2bf(s);
    uh[idx] = h;
    ul[idx] = f2bf(s - bf2f(h));
}

// ---------------------------------------------------------------------------
// x_proj via MFMA, split-precision (uh+ul)@(Wh+Wl), K split 8 ways.
__global__ __launch_bounds__(64) void xproj_mfma(
    const unsigned short* __restrict__ uh, const unsigned short* __restrict__ ul,
    const unsigned short* __restrict__ Wh, const unsigned short* __restrict__ Wl,
    float* __restrict__ part)
{
    const int lane = threadIdx.x;
    const int bid = blockIdx.x;          // 2048 = 256 mb x 8 ks
    const int ks = bid & (KSP - 1);
    const int mb = bid >> 3;
    const int row0 = mb * 16;
    const int k0 = ks * (DI / KSP);
    const int fr = lane & 15, kg = (lane >> 4) * 8;

    f32x4 acc[6];
    #pragma unroll
    for (int j = 0; j < 6; ++j) acc[j] = (f32x4){0.f, 0.f, 0.f, 0.f};

    for (int kk = 0; kk < DI / KSP; kk += 32) {
        const size_t abase = (size_t)(row0 + fr) * DI + k0 + kk + kg;
        bf16x8 ah = *(const bf16x8*)&uh[abase];
        bf16x8 al = *(const bf16x8*)&ul[abase];
        #pragma unroll
        for (int j = 0; j < 6; ++j) {
            const size_t bbase = (size_t)(j * 16 + fr) * DI + k0 + kk + kg;
            bf16x8 bh = *(const bf16x8*)&Wh[bbase];
            bf16x8 bl = *(const bf16x8*)&Wl[bbase];
            acc[j] = __builtin_amdgcn_mfma_f32_16x16x32_bf16(ah, bh, acc[j], 0, 0, 0);
            acc[j] = __builtin_amdgcn_mfma_f32_16x16x32_bf16(al, bh, acc[j], 0, 0, 0);
            acc[j] = __builtin_amdgcn_mfma_f32_16x16x32_bf16(ah, bl, acc[j], 0, 0, 0);
        }
    }
    const int rq = lane >> 4;
    #pragma unroll
    for (int j = 0; j < 6; ++j) {
        int col = j * 16 + fr;
        #pragma unroll
        for (int r = 0; r < 4; ++r) {
            int row = row0 + rq * 4 + r;
            part[((size_t)ks * NTOK + row) * XD + col] = acc[j][r];
        }
    }
}

// reduce K-split partials; also emit delta cols (0..63) as bf16 hi/lo for dtproj
__global__ __launch_bounds__(256) void xproj_reduce(const float* __restrict__ part,
    float* __restrict__ xdbl, unsigned short* __restrict__ dxh, unsigned short* __restrict__ dxl)
{
    int i = blockIdx.x * 256 + threadIdx.x;    // NTOK*XD = 393216
    float s = 0.f;
    #pragma unroll
    for (int ks = 0; ks < KSP; ++ks)
        s += part[(size_t)ks * ((size_t)NTOK * XD) + i];
    xdbl[i] = s;
    int row = i / XD;
    int col = i - row * XD;
    if (col < DTR) {
        unsigned short h = f2bf(s);
        size_t o = (size_t)row * DTR + col;
        dxh[o] = h;
        dxl[o] = f2bf(s - bf2f(h));
    }
}

// ---------------------------------------------------------------------------
// dt_proj + softplus via MFMA, split precision.  1 wave/block,
// 16 tokens x 128 cols, K=64 in 2 steps of 32, 3 MFMAs per fragment.
__global__ __launch_bounds__(64) void dtproj_mfma(
    const unsigned short* __restrict__ dxh, const unsigned short* __restrict__ dxl,
    const unsigned short* __restrict__ Wh, const unsigned short* __restrict__ Wl,
    const float* __restrict__ dtb, float* __restrict__ dt)
{
    const int lane = threadIdx.x;
    const int bid = blockIdx.x;          // 4096 = 256 mb x 16 nb
    const int nb = bid & 15;
    const int mb = bid >> 4;
    const int row0 = mb * 16;
    const int col0 = nb * 128;
    const int fr = lane & 15, kg = (lane >> 4) * 8;

    f32x4 acc[8];
    #pragma unroll
    for (int j = 0; j < 8; ++j) acc[j] = (f32x4){0.f, 0.f, 0.f, 0.f};

    #pragma unroll
    for (int kk = 0; kk < DTR; kk += 32) {
        const size_t abase = (size_t)(row0 + fr) * DTR + kk + kg;
        bf16x8 ah = *(const bf16x8*)&dxh[abase];
        bf16x8 al = *(const bf16x8*)&dxl[abase];
        #pragma unroll
        for (int j = 0; j < 8; ++j) {
            const size_t bbase = (size_t)(col0 + j * 16 + fr) * DTR + kk + kg;
            bf16x8 bh = *(const bf16x8*)&Wh[bbase];
            bf16x8 bl = *(const bf16x8*)&Wl[bbase];
            acc[j] = __builtin_amdgcn_mfma_f32_16x16x32_bf16(ah, bh, acc[j], 0, 0, 0);
            acc[j] = __builtin_amdgcn_mfma_f32_16x16x32_bf16(al, bh, acc[j], 0, 0, 0);
            acc[j] = __builtin_amdgcn_mfma_f32_16x16x32_bf16(ah, bl, acc[j], 0, 0, 0);
        }
    }
    const int rq = lane >> 4;
    #pragma unroll
    for (int j = 0; j < 8; ++j) {
        int col = col0 + j * 16 + fr;
        float bias = dtb[col];
        #pragma unroll
        for (int r = 0; r < 4; ++r) {
            int row = row0 + rq * 4 + r;
            float v = acc[j][r] + bias;
            float sp = (v > 20.0f) ? v : __logf(1.0f + __expf(v));
            dt[(size_t)row * DI + col] = sp;
        }
    }
}

// ---------------------------------------------------------------------------
// Chunked selective scan (3 passes).  n-split 2x (8 states/thread) + __expf.
__global__ __launch_bounds__(256) void scan_passA(
    const float* __restrict__ dt, const float* __restrict__ uc,
    const float* __restrict__ xdbl, const float* __restrict__ A_log,
    float* __restrict__ hA, float* __restrict__ PA)
{
    const int tid = threadIdx.x;
    const int bid = blockIdx.x;            // 1024 = B * NCH * 16
    const int dblk = bid & 15;
    const int c = (bid >> 4) & (NCH - 1);
    const int b = bid >> 9;
    const int di = tid >> 1, hf = tid & 1;
    const int d = dblk * 128 + di;
    const size_t t0 = (size_t)b * L_ + (size_t)c * CH;

    float Av[8];
    {
        const float4* ap = (const float4*)(A_log + (size_t)d * NST + hf * 8);
        float4 a0 = ap[0], a1 = ap[1];
        Av[0]=-expf(a0.x); Av[1]=-expf(a0.y); Av[2]=-expf(a0.z); Av[3]=-expf(a0.w);
        Av[4]=-expf(a1.x); Av[5]=-expf(a1.y); Av[6]=-expf(a1.z); Av[7]=-expf(a1.w);
    }
    float h[8], P[8];
    #pragma unroll
    for (int n = 0; n < 8; ++n) { h[n] = 0.f; P[n] = 1.f; }

    float dtv[4], uv[4];
    float4 Bq[2][2];
    #pragma unroll
    for (int j = 0; j < 4; ++j) {
        size_t t = t0 + j;
        dtv[j] = dt[t * DI + d];
        uv[j]  = uc[t * DI + d];
    }
    #pragma unroll
    for (int j = 0; j < 2; ++j) {
        const float4* xr = (const float4*)(xdbl + (t0 + j) * XD + DTR + hf * 8);
        Bq[j][0] = xr[0]; Bq[j][1] = xr[1];
    }

    #pragma unroll 4
    for (int l = 0; l < CH; ++l) {
        const int s2 = l & 1, s4 = l & 3;
        float dtc = dtv[s4], uvc = uv[s4];
        float bc[8];
        bc[0]=Bq[s2][0].x; bc[1]=Bq[s2][0].y; bc[2]=Bq[s2][0].z; bc[3]=Bq[s2][0].w;
        bc[4]=Bq[s2][1].x; bc[5]=Bq[s2][1].y; bc[6]=Bq[s2][1].z; bc[7]=Bq[s2][1].w;
        if (l + 4 < CH) {
            size_t t = t0 + l + 4;
            dtv[s4] = dt[t * DI + d];
            uv[s4]  = uc[t * DI + d];
        }
        if (l + 2 < CH) {
            const float4* xr = (const float4*)(xdbl + (t0 + l + 2) * XD + DTR + hf * 8);
            Bq[s2][0] = xr[0]; Bq[s2][1] = xr[1];
        }
        float dtu = dtc * uvc;
        #pragma unroll
        for (int n = 0; n < 8; ++n) {
            float dA = __expf(dtc * Av[n]);
            h[n] = fmaf(dA, h[n], dtu * bc[n]);
            P[n] *= dA;
        }
    }
    size_t obase = ((size_t)(b * NCH + c) * DI + d) * NST + hf * 8;
    float4* hp = (float4*)&hA[obase];
    hp[0] = make_float4(h[0], h[1], h[2], h[3]);
    hp[1] = make_float4(h[4], h[5], h[6], h[7]);
    float4* pp = (float4*)&PA[obase];
    pp[0] = make_float4(P[0], P[1], P[2], P[3]);
    pp[1] = make_float4(P[4], P[5], P[6], P[7]);
}

__global__ __launch_bounds__(256) void scan_passB(
    const float* __restrict__ hA, const float* __restrict__ PA,
    float* __restrict__ hin)
{
    int g = blockIdx.x * 256 + threadIdx.x;
    int b = g >> 15;
    int rest = g & 32767;
    float h = 0.f;
    for (int c = 0; c < NCH; ++c) {
        size_t idx = ((size_t)(b * NCH + c) * DI) * NST + rest;
        hin[idx] = h;
        h = fmaf(PA[idx], h, hA[idx]);
    }
}

__global__ __launch_bounds__(256) void scan_passC(
    const float* __restrict__ dt, const float* __restrict__ uc,
    const float* __restrict__ xdbl, const float* __restrict__ xz,
    const float* __restrict__ A_log, const float* __restrict__ Dp,
    const float* __restrict__ hin, unsigned short* __restrict__ yg)
{
    const int tid = threadIdx.x;
    const int bid = blockIdx.x;            // 1024 = B * NCH * 16
    const int dblk = bid & 15;
    const int c = (bid >> 4) & (NCH - 1);
    const int b = bid >> 9;
    const int di = tid >> 1, hf = tid & 1;
    const int d = dblk * 128 + di;
    const size_t t0 = (size_t)b * L_ + (size_t)c * CH;

    float Av[8];
    {
        const float4* ap = (const float4*)(A_log + (size_t)d * NST + hf * 8);
        float4 a0 = ap[0], a1 = ap[1];
        Av[0]=-expf(a0.x); Av[1]=-expf(a0.y); Av[2]=-expf(a0.z); Av[3]=-expf(a0.w);
        Av[4]=-expf(a1.x); Av[5]=-expf(a1.y); Av[6]=-expf(a1.z); Av[7]=-expf(a1.w);
    }
    const float Dv = Dp[d];
    float h[8];
    {
        size_t ibase = ((size_t)(b * NCH + c) * DI + d) * NST + hf * 8;
        const float4* hp = (const float4*)&hin[ibase];
        float4 h0 = hp[0], h1 = hp[1];
        h[0]=h0.x; h[1]=h0.y; h[2]=h0.z; h[3]=h0.w;
        h[4]=h1.x; h[5]=h1.y; h[6]=h1.z; h[7]=h1.w;
    }

    float dtv[4], uv[4], rv[4];
    float4 Bq[2][2], Cq[2][2];
    #pragma unroll
    for (int j = 0; j < 4; ++j) {
        size_t t = t0 + j;
        dtv[j] = dt[t * DI + d];
        uv[j]  = uc[t * DI + d];
        rv[j]  = xz[(t << 12) + DI + d];
    }
    #pragma unroll
    for (int j = 0; j < 2; ++j) {
        const float4* xr = (const float4*)(xdbl + (t0 + j) * XD + DTR + hf * 8);
        Bq[j][0] = xr[0]; Bq[j][1] = xr[1];
        Cq[j][0] = xr[4]; Cq[j][1] = xr[5];   // C is 16 floats after B
    }

    #pragma unroll 4
    for (int l = 0; l < CH; ++l) {
        const int s2 = l & 1, s4 = l & 3;
        float dtc = dtv[s4], uvc = uv[s4], rvc = rv[s4];
        float bc[8], cc[8];
        bc[0]=Bq[s2][0].x; bc[1]=Bq[s2][0].y; bc[2]=Bq[s2][0].z; bc[3]=Bq[s2][0].w;
        bc[4]=Bq[s2][1].x; bc[5]=Bq[s2][1].y; bc[6]=Bq[s2][1].z; bc[7]=Bq[s2][1].w;
        cc[0]=Cq[s2][0].x; cc[1]=Cq[s2][0].y; cc[2]=Cq[s2][0].z; cc[3]=Cq[s2][0].w;
        cc[4]=Cq[s2][1].x; cc[5]=Cq[s2][1].y; cc[6]=Cq[s2][1].z; cc[7]=Cq[s2][1].w;
        if (l + 4 < CH) {
            size_t t = t0 + l + 4;
            dtv[s4] = dt[t * DI + d];
            uv[s4]  = uc[t * DI + d];
            rv[s4]  = xz[(t << 12) + DI + d];
        }
        if (l + 2 < CH) {
            const float4* xr = (const float4*)(xdbl + (t0 + l + 2) * XD + DTR + hf * 8);
            Bq[s2][0] = xr[0]; Bq[s2][1] = xr[1];
            Cq[s2][0] = xr[4]; Cq[s2][1] = xr[5];
        }
        float dtu = dtc * uvc;
        float p = 0.f;
        #pragma unroll
        for (int n = 0; n < 8; ++n) {
            float dA = __expf(dtc * Av[n]);
            h[n] = fmaf(dA, h[n], dtu * bc[n]);
            p = fmaf(h[n], cc[n], p);
        }
        p += __shfl_xor(p, 1);
        if (hf == 0) {
            float y = fmaf(uvc, Dv, p);
            float sig = 1.0f / (1.0f + __expf(-rvc));
            yg[(t0 + l) * DI + d] = f2bf(y * rvc * sig);
        }
    }
}

// ---------------------------------------------------------------------------
extern "C" void kernel_launch(void* const* d_in, const int* in_sizes, int n_in,
                              void* d_out, int out_size, void* d_ws, size_t ws_size,
                              hipStream_t stream)
{
    const float* x    = (const float*)d_in[0];
    const float* nw   = (const float*)d_in[1];
    const float* ipw  = (const float*)d_in[2];
    const float* cw   = (const float*)d_in[3];
    const float* cb   = (const float*)d_in[4];
    const float* xpw  = (const float*)d_in[5];
    const float* dtw  = (const float*)d_in[6];
    const float* dtb  = (const float*)d_in[7];
    const float* alog = (const float*)d_in[8];
    const float* dpar = (const float*)d_in[9];
    const float* opw  = (const float*)d_in[10];
    float* out = (float*)d_out;

    char* p = (char*)d_ws;
    float* xz    = (float*)p;  p += (size_t)NTOK * 2 * DI * 4;       // 67.1 MB
    float* uc    = (float*)p;  p += (size_t)NTOK * DI * 4;           // 33.6 MB
    float* xdbl  = (float*)p;  p += (size_t)NTOK * XD * 4;           //  1.6 MB
    float* dtbuf = (float*)p;  p += (size_t)NTOK * DI * 4;           // 33.6 MB
    float* hin   = (float*)p;  p += (size_t)B_ * NCH * DI * NST * 4; //  8.4 MB
    unsigned short* yg   = (unsigned short*)p;  p += (size_t)NTOK * DI * 2;   // 16.8 MB
    unsigned short* xnb  = (unsigned short*)p;  p += (size_t)NTOK * DM * 2;   //  8.4 MB
    unsigned short* ipwt = (unsigned short*)p;  p += (size_t)DM * 2 * DI * 2; //  8.4 MB
    unsigned short* opwt = (unsigned short*)p;  p += (size_t)DI * DM * 2;     //  4.2 MB
    unsigned short* xpwh = (unsigned short*)p;  p += (size_t)XD * DI * 2;     //  0.4 MB
    unsigned short* xpwl = (unsigned short*)p;  p += (size_t)XD * DI * 2;     //  0.4 MB
    unsigned short* dtwh = (unsigned short*)p;  p += (size_t)DI * DTR * 2;    //  0.26 MB
    unsigned short* dtwl = (unsigned short*)p;  p += (size_t)DI * DTR * 2;    //  0.26 MB
    unsigned short* dxh  = (unsigned short*)p;  p += (size_t)NTOK * DTR * 2;  //  0.5 MB
    unsigned short* dxl  = (unsigned short*)p;  p += (size_t)NTOK * DTR * 2;  //  0.5 MB
    // aliases (stream-ordered lifetimes):
    float* hA = (float*)xnb;                 // scan A out (dead after B); xnb dead after gemm1
    float* PA = (float*)ipwt;                // ipwt dead after gemm1
    unsigned short* uh = (unsigned short*)dtbuf;              // dead before dtproj writes
    unsigned short* ul = (unsigned short*)(dtbuf + (size_t)NTOK * DI / 2);
    float* part = (float*)yg;                // xproj partials; yg written later in passC

    transpose_cast<<<dim3(2 * DI / 32, DM / 32), 256, 0, stream>>>(ipw, ipwt, DM, 2 * DI);
    transpose_cast<<<dim3(DM / 32, DI / 32), 256, 0, stream>>>(opw, opwt, DI, DM);
    transpose_cast_hl<<<dim3(XD / 32, DI / 32), 256, 0, stream>>>(xpw, xpwh, xpwl, DI, XD);
    transpose_cast_hl<<<dim3(DI / 32, DTR / 32), 256, 0, stream>>>(dtw, dtwh, dtwl, DTR, DI);

    rmsnorm_bf16<<<NTOK, 256, 0, stream>>>(x, nw, xnb);

    gemm_bf16t<<<dim3(2 * DI / 128, NTOK / 128), 256, 0, stream>>>(xnb, ipwt, xz, NTOK, 2 * DI, DM);

    conv_silu_kernel<<<NTOK * DI / 256, 256, 0, stream>>>(xz, cw, cb, uc, uh, ul);

    xproj_mfma<<<(NTOK / 16) * KSP, 64, 0, stream>>>(uh, ul, xpwh, xpwl, part);
    xproj_reduce<<<NTOK * XD / 256, 256, 0, stream>>>(part, xdbl, dxh, dxl);

    dtproj_mfma<<<(NTOK / 16) * (DI / 128), 64, 0, stream>>>(dxh, dxl, dtwh, dtwl, dtb, dtbuf);

    scan_passA<<<B_ * NCH * (DI / 128), 256, 0, stream>>>(dtbuf, uc, xdbl, alog, hA, PA);
    scan_passB<<<B_ * DI * NST / 256, 256, 0, stream>>>(hA, PA, hin);
    scan_passC<<<B_ * NCH * (DI / 128), 256, 0, stream>>>(dtbuf, uc, xdbl, xz, alog, dpar, hin, yg);

    gemm_bf16t<<<dim3(DM / 128, NTOK / 128), 256, 0, stream>>>(yg, opwt, out, NTOK, DM, DI);
}